// Round 12
// baseline (379.171 us; speedup 1.0000x reference)
//
#include <hip/hip_runtime.h>
#include <hip/hip_bf16.h>
#include <cstdint>
#include <cstddef>

typedef __hip_bfloat16 bf16;
typedef __attribute__((ext_vector_type(8))) short short8;
typedef __attribute__((ext_vector_type(4))) float f32x4;

#define B_  2
#define T_  2048
#define E_  1024
#define H_  16
#define HS_ 64
#define EPS_ 1e-5f
#define NEG_BIG -1.0e30f
// 0.125 (1/sqrt(64)) * log2(e): scores in exp2 domain
#define SCL2E 0.18033688011112042f

__device__ __forceinline__ float b2f(bf16 v) { return __bfloat162float(v); }
__device__ __forceinline__ bf16  f2b(float v) { return __float2bfloat16(v); }
__device__ __forceinline__ ushort f2bs(float v) { bf16 b = __float2bfloat16(v); return *(ushort*)&b; }
__device__ __forceinline__ float ld1(const bf16* p) { return b2f(*p); }
__device__ __forceinline__ float ld1(const float* p) { return *p; }
__device__ __forceinline__ void st1(bf16* p, float v) { *p = f2b(v); }
__device__ __forceinline__ void st1(float* p, float v) { *p = v; }

// vectorized 4-elem load/store helpers (G13: no scalar bf16 loads)
__device__ __forceinline__ void ld4(const bf16* p, float v[4]) {
    ushort4 u = *(const ushort4*)p;
    v[0] = b2f(*(const bf16*)&u.x);
    v[1] = b2f(*(const bf16*)&u.y);
    v[2] = b2f(*(const bf16*)&u.z);
    v[3] = b2f(*(const bf16*)&u.w);
}
__device__ __forceinline__ void ld4(const float* p, float v[4]) {
    float4 f = *(const float4*)p;
    v[0] = f.x; v[1] = f.y; v[2] = f.z; v[3] = f.w;
}
__device__ __forceinline__ void st4(bf16* p, const float v[4]) {
    ushort4 u;
    u.x = f2bs(v[0]); u.y = f2bs(v[1]); u.z = f2bs(v[2]); u.w = f2bs(v[3]);
    *(ushort4*)p = u;
}
__device__ __forceinline__ void st4(float* p, const float v[4]) {
    float4 f; f.x = v[0]; f.y = v[1]; f.z = v[2]; f.w = v[3];
    *(float4*)p = f;
}

__device__ __forceinline__ float fexp2(float x) {
#if __has_builtin(__builtin_amdgcn_exp2f)
    return __builtin_amdgcn_exp2f(x);
#else
    return exp2f(x);
#endif
}

// async global->LDS, 16B per lane; lds dest = wave-uniform base + lane*16
__device__ __forceinline__ void gload16(const void* g, const void* l) {
    __builtin_amdgcn_global_load_lds(
        (const __attribute__((address_space(1))) unsigned int*)(size_t)g,
        (__attribute__((address_space(3))) unsigned int*)(unsigned int)(size_t)l,
        16, 0, 0);
}

// ---------------------------------------------------------------------------
// 64x64 fp32->bf16 transpose tile (shared buffer passed in)
// ---------------------------------------------------------------------------
__device__ __forceinline__ void transpose_tile_s(short t[64][72],
                                                 const float* in, size_t ldin,
                                                 bf16* out, size_t ldout,
                                                 int r0, int c0)
{
    const int tid = threadIdx.x;
    const int tr = tid >> 2, tc4 = (tid & 3) * 16;

    const float* p = in + (size_t)(r0 + tr) * ldin + c0 + tc4;
    float4 v0 = ((const float4*)p)[0], v1 = ((const float4*)p)[1];
    float4 v2 = ((const float4*)p)[2], v3 = ((const float4*)p)[3];
    union { ushort u[16]; uint4 q[2]; } pk;
    pk.u[0] = f2bs(v0.x); pk.u[1] = f2bs(v0.y); pk.u[2]  = f2bs(v0.z); pk.u[3]  = f2bs(v0.w);
    pk.u[4] = f2bs(v1.x); pk.u[5] = f2bs(v1.y); pk.u[6]  = f2bs(v1.z); pk.u[7]  = f2bs(v1.w);
    pk.u[8] = f2bs(v2.x); pk.u[9] = f2bs(v2.y); pk.u[10] = f2bs(v2.z); pk.u[11] = f2bs(v2.w);
    pk.u[12] = f2bs(v3.x); pk.u[13] = f2bs(v3.y); pk.u[14] = f2bs(v3.z); pk.u[15] = f2bs(v3.w);
    *(uint4*)&t[tr][tc4]     = pk.q[0];
    *(uint4*)&t[tr][tc4 + 8] = pk.q[1];
    __syncthreads();

    const int tcI = tid >> 2, rj = (tid & 3) * 16;
    union { ushort u[16]; uint4 q[2]; } po;
    #pragma unroll
    for (int j = 0; j < 16; j++) po.u[j] = (ushort)t[rj + j][tcI];
    bf16* op = out + (size_t)(c0 + tcI) * ldout + r0 + rj;
    ((uint4*)op)[0] = po.q[0];
    ((uint4*)op)[1] = po.q[1];
}

// ---------------------------------------------------------------------------
// Merged prep A: x->bf16 (2048 blocks) + Wqkv^T (768) + Wo^T (256)
// ---------------------------------------------------------------------------
__global__ __launch_bounds__(256) void prep_kernel(const float* __restrict__ x,
                                                   ushort* __restrict__ xb,
                                                   const float* __restrict__ Wq,
                                                   const float* __restrict__ Wk,
                                                   const float* __restrict__ Wv,
                                                   bf16* __restrict__ WqkvT,
                                                   const float* __restrict__ Wo,
                                                   bf16* __restrict__ WoT)
{
    __shared__ short t[64][72];
    const int bid = blockIdx.x;
    if (bid < 2048) {
        int i = (bid * 256 + (int)threadIdx.x) * 8;
        float4 a = ((const float4*)(x + i))[0];
        float4 b = ((const float4*)(x + i))[1];
        union { ushort u[8]; uint4 v; } p;
        p.u[0] = f2bs(a.x); p.u[1] = f2bs(a.y); p.u[2] = f2bs(a.z); p.u[3] = f2bs(a.w);
        p.u[4] = f2bs(b.x); p.u[5] = f2bs(b.y); p.u[6] = f2bs(b.z); p.u[7] = f2bs(b.w);
        *(uint4*)(xb + i) = p.v;
    } else if (bid < 2048 + 768) {
        const int i = bid - 2048;            // (s 0..47) x (xt 0..15)
        const int s = i >> 4, xt = i & 15;
        const int proj = s >> 4, h = s & 15;
        const float* W = (proj == 0) ? Wq : ((proj == 1) ? Wk : Wv);
        transpose_tile_s(t, W + (size_t)h * E_ * HS_, HS_,
                         WqkvT + ((size_t)proj * E_ + h * 64) * E_, E_,
                         xt * 64, 0);
    } else {
        const int i = bid - 2816;            // 256 tiles of Wo [1024][1024]
        transpose_tile_s(t, Wo, E_, WoT, E_, (i >> 4) * 64, (i & 15) * 64);
    }
}

// ---------------------------------------------------------------------------
// Merged prep B: W1^T (1024 blocks) + W2^T (1024 blocks)
// ---------------------------------------------------------------------------
__global__ __launch_bounds__(256) void prep2_kernel(const float* __restrict__ W1,
                                                    bf16* __restrict__ W1T,
                                                    const float* __restrict__ W2,
                                                    bf16* __restrict__ W2T)
{
    __shared__ short t[64][72];
    const int bid = blockIdx.x;
    if (bid < 1024) {   // W1 [1024][4096] -> W1T [4096][1024]
        transpose_tile_s(t, W1, 4 * E_, W1T, E_,
                         (bid & 15) * 64, (bid >> 4) * 64);
    } else {            // W2 [4096][1024] -> W2T [1024][4096]
        const int i = bid - 1024;
        transpose_tile_s(t, W2, E_, W2T, 4 * E_,
                         (i >> 4) * 64, (i & 15) * 64);
    }
}

// ---------------------------------------------------------------------------
// MFMA GEMM: C[M,N] = A[M,K] @ BT[N,K]^T (+bias fp32)(+relu)(+C-accumulate),
// bf16 in, TO out. BT row stride = ldb (>= K; enables K-sliced B operands).
// XCD-pinned bijective grid remap (requires gridDim.x % 8 == 0).
// VSPLIT (qkv call only): blocks with col0 >= 2048 hold the V-projection;
// instead of writing C they write vT [bh][64][T] directly (transposed) —
// 4 consecutive t-rows per lane pack into one 8B ushort4 store. This fuses
// the old vt_transpose kernel into the epilogue (qkv's V-section was never
// read by anything else).
// ---------------------------------------------------------------------------
template <int WROWS, int WCOLS, int MF, int NF, int KS, bool BIAS, bool RELU,
          bool ACC, bool VSPLIT, typename TO>
__global__ __launch_bounds__(256) void gemm_bt(const bf16* __restrict__ A,
                                               const bf16* __restrict__ BT,
                                               const float* __restrict__ bias,
                                               TO* __restrict__ C,
                                               bf16* __restrict__ vTout,
                                               int M, int N, int K, int ldb)
{
    constexpr int BM = WROWS * MF * 16;
    constexpr int BN = WCOLS * NF * 16;
    __shared__ short Asm[KS][BM][32];
    __shared__ short Bsm[KS][BN][32];

    const int tid  = threadIdx.x;
    const int wv   = tid >> 6, lane = tid & 63;
    const int quad = lane >> 4, l16 = lane & 15;

    // XCD-pinned bijective remap (gx % 8 == 0 at every call site)
    const int gx = gridDim.x;
    const int p  = blockIdx.y * gx + blockIdx.x;
    const int spx = gx >> 3;                 // column strips per XCD
    const int xcd = p & 7, j = p >> 3;
    const int bx = xcd * spx + (j % spx);
    const int by = j / spx;

    const int row0 = by * BM, col0 = bx * BN;
    const int mr0  = (wv / WCOLS) * MF * 16;
    const int nc0  = (wv % WCOLS) * NF * 16;

    const int sr = tid >> 2, sc = tid & 3;
    const bf16* Ag = A  + (size_t)(row0 + sr) * K + sc * 8;
    const bf16* Bg = BT + (size_t)(col0 + (sr % BN)) * ldb + sc * 8;

    f32x4 acc[MF][NF];
    #pragma unroll
    for (int i = 0; i < MF; i++)
        #pragma unroll
        for (int j2 = 0; j2 < NF; j2++) acc[i][j2] = (f32x4){0.f, 0.f, 0.f, 0.f};

    for (int kt = 0; kt < K; kt += 32 * KS) {
        __syncthreads();
        #pragma unroll
        for (int g = 0; g < KS; g++) {
            #pragma unroll
            for (int l = 0; l < BM / 64; l++)
                gload16(Ag + g * 32 + (size_t)l * 64 * K, &Asm[g][l * 64 + wv * 16][0]);
            #pragma unroll
            for (int l = 0; l < BN / 64; l++)
                gload16(Bg + g * 32 + (size_t)l * 64 * ldb, &Bsm[g][l * 64 + wv * 16][0]);
        }
        Ag += 32 * KS; Bg += 32 * KS;
        __syncthreads();

        #pragma unroll
        for (int g = 0; g < KS; g++) {
            short8 af[MF], bfr[NF];
            #pragma unroll
            for (int mf = 0; mf < MF; mf++)
                af[mf] = *(const short8*)&Asm[g][mr0 + mf * 16 + l16][quad * 8];
            #pragma unroll
            for (int nf = 0; nf < NF; nf++)
                bfr[nf] = *(const short8*)&Bsm[g][nc0 + nf * 16 + l16][quad * 8];
            #pragma unroll
            for (int mf = 0; mf < MF; mf++)
                #pragma unroll
                for (int nf = 0; nf < NF; nf++)
                    acc[mf][nf] = __builtin_amdgcn_mfma_f32_16x16x32_bf16(
                        af[mf], bfr[nf], acc[mf][nf], 0, 0, 0);
        }
    }

    if (VSPLIT && col0 >= 2 * E_) {
        // V-projection tile -> write vT [bh][64][T] transposed.
        // acc[mf][nf][r]: row = row0+mr0+mf*16+quad*4+r (global token index),
        // col = col0+nc0+nf*16+l16 (2048 + h*64 + d). 4 r-values are 4
        // consecutive t at the same d -> one ushort4 (8B) store.
        #pragma unroll
        for (int nf = 0; nf < NF; nf++) {
            const int cv = col0 + nc0 + nf * 16 + l16 - 2 * E_;
            const int hh = cv >> 6, dd = cv & 63;
            #pragma unroll
            for (int mf = 0; mf < MF; mf++) {
                const int row = row0 + mr0 + mf * 16 + quad * 4;
                const int bb = row >> 11, tt = row & (T_ - 1);
                ushort4 u;
                u.x = f2bs(acc[mf][nf][0]);
                u.y = f2bs(acc[mf][nf][1]);
                u.z = f2bs(acc[mf][nf][2]);
                u.w = f2bs(acc[mf][nf][3]);
                *(ushort4*)(vTout + ((size_t)(bb * H_ + hh) * 64 + dd) * T_ + tt) = u;
            }
        }
    } else {
        #pragma unroll
        for (int nf = 0; nf < NF; nf++) {
            const int col = col0 + nc0 + nf * 16 + l16;
            const float bv = BIAS ? bias[col] : 0.f;
            #pragma unroll
            for (int mf = 0; mf < MF; mf++) {
                #pragma unroll
                for (int r = 0; r < 4; r++) {
                    const int row = row0 + mr0 + mf * 16 + quad * 4 + r;
                    float v = acc[mf][nf][r] + bv;
                    if (ACC) v += ld1(&C[(size_t)row * N + col]);
                    if (RELU) v = fmaxf(v, 0.f);
                    st1(&C[(size_t)row * N + col], v);
                }
            }
        }
    }
}

// ---------------------------------------------------------------------------
// Flash attention (best measured config, 58 us): 128-key stages, no setprio,
// unpaired 1024-block grid, XCD-pinned (bh by p%8), heavy-first tiles,
// direct global->LDS staging (no reg arrays across barriers), swapped-QK
// lane-local softmax, ones-column denominator, exp2 domain.
// ---------------------------------------------------------------------------
__global__ __launch_bounds__(256) void attn_mfma(const bf16* __restrict__ qkv,
                                                 const bf16* __restrict__ vT,
                                                 bf16* __restrict__ outp)
{
    __shared__ short Klds[128][72];
    __shared__ short Vlds[64][136];
    __shared__ short Plds[4][16][136];

    const int tid  = threadIdx.x;
    const int w    = tid >> 6, lane = tid & 63;
    const int quad = lane >> 4, l16 = lane & 15;

    const int p    = blockIdx.y * 32 + blockIdx.x;   // 1024 blocks
    const int bh   = (p & 7) * 4 + ((p >> 3) & 3);   // XCD-pinned by p%8
    const int tile = 31 - (p >> 5);                  // heavy-first
    const int b    = bh >> 4, h = bh & 15;
    const size_t rowb = (size_t)b * T_ * 3 * E_;
    const int t0    = tile * 64;
    const int qbase = t0 + w * 16;

    // K staging map: key = tid>>1 (0..127), d-half = (tid&1)*32
    const int kkey = tid >> 1, kdh = (tid & 1) * 32;
    const bf16* Kg = qkv + rowb + E_ + h * HS_ + kdh;
    // V staging map: d = tid>>2 (0..63), key-seg = (tid&3)*32
    const int vd = tid >> 2, vseg = (tid & 3) * 32;
    const bf16* Vg = vT + ((size_t)bh * 64 + vd) * T_ + vseg;

    short8 vone;
    #pragma unroll
    for (int j = 0; j < 8; j++) vone[j] = (short)0x3F80;   // bf16 1.0

    const bf16* Qp = qkv + rowb + (size_t)(qbase + l16) * (3 * E_) + h * HS_;
    const short8 aq0 = *(const short8*)(Qp + quad * 8);
    const short8 aq1 = *(const short8*)(Qp + 32 + quad * 8);

    f32x4 o[4], o4;
    #pragma unroll
    for (int f = 0; f < 4; f++) o[f] = (f32x4){0.f, 0.f, 0.f, 0.f};
    o4 = (f32x4){0.f, 0.f, 0.f, 0.f};
    float mrow = NEG_BIG;

    for (int kt0 = 0; kt0 <= t0; kt0 += 128) {
        __syncthreads();   // all reads of prev K/Vlds done
        {
            // DIRECT load->LDS staging: transient regs only,
            // no named arrays living across a barrier.
            const int kr = (kt0 + kkey < T_) ? kt0 + kkey : T_ - 1;
            const bf16* kp = Kg + (size_t)kr * (3 * E_);
            *(uint4*)&Klds[kkey][kdh]      = ((const uint4*)kp)[0];
            *(uint4*)&Klds[kkey][kdh + 8]  = ((const uint4*)kp)[1];
            *(uint4*)&Klds[kkey][kdh + 16] = ((const uint4*)kp)[2];
            *(uint4*)&Klds[kkey][kdh + 24] = ((const uint4*)kp)[3];
            const bf16* vp = Vg + kt0;
            *(uint4*)&Vlds[vd][vseg]       = ((const uint4*)vp)[0];
            *(uint4*)&Vlds[vd][vseg + 8]   = ((const uint4*)vp)[1];
            *(uint4*)&Vlds[vd][vseg + 16]  = ((const uint4*)vp)[2];
            *(uint4*)&Vlds[vd][vseg + 24]  = ((const uint4*)vp)[3];
        }
        __syncthreads();   // staging visible

        const bool active = (kt0 <= qbase + 15);       // wave-uniform
        const int nv0 = ((qbase + 15 - kt0) >> 4) + 1; // valid chunks
        const int nvalid = active ? (nv0 < 8 ? nv0 : 8) : 0;

        // swapped QK^T: ps[c][r] = S[qrow=qbase+l16][key=kt0+c*16+quad*4+r]
        float ps[8][4];
        #pragma unroll
        for (int c = 0; c < 8; c++) {
            if (c < nvalid) {
                const int kc = kt0 + c * 16;
                const int krow = c * 16 + l16;
                short8 bk0 = *(const short8*)&Klds[krow][quad * 8];
                short8 bk1 = *(const short8*)&Klds[krow][32 + quad * 8];
                f32x4 s = (f32x4){0.f, 0.f, 0.f, 0.f};
                s = __builtin_amdgcn_mfma_f32_16x16x32_bf16(bk0, aq0, s, 0, 0, 0);
                s = __builtin_amdgcn_mfma_f32_16x16x32_bf16(bk1, aq1, s, 0, 0, 0);
                const bool needmask = (kc + 15 > qbase);   // wave-uniform
                #pragma unroll
                for (int r = 0; r < 4; r++) {
                    float sv = s[r] * SCL2E;
                    if (needmask && (kc + quad * 4 + r > qbase + l16)) sv = NEG_BIG;
                    ps[c][r] = sv;
                }
            }
        }
        if (active) {
            // lane-local max (lane's own keys) + cross-quad combine:
            // after 2 shfl, every lane holds the full max of q-row l16.
            float mx = ps[0][0];
            #pragma unroll
            for (int r = 1; r < 4; r++) mx = fmaxf(mx, ps[0][r]);
            #pragma unroll
            for (int c = 1; c < 8; c++)
                if (c < nvalid)
                    #pragma unroll
                    for (int r = 0; r < 4; r++) mx = fmaxf(mx, ps[c][r]);
            mx = fmaxf(mx, __shfl_xor(mx, 16));
            mx = fmaxf(mx, __shfl_xor(mx, 32));
            const float mnew = fmaxf(mrow, mx);
            const float al = fexp2(mrow - mnew);
            mrow = mnew;

            // P = exp2(s - m); 4 consecutive keys -> one b64 LDS write
            #pragma unroll
            for (int c = 0; c < 8; c++) {
                uint2 pk; pk.x = 0u; pk.y = 0u;
                if (c < nvalid) {
                    const float e0 = fexp2(ps[c][0] - mnew);
                    const float e1 = fexp2(ps[c][1] - mnew);
                    const float e2 = fexp2(ps[c][2] - mnew);
                    const float e3 = fexp2(ps[c][3] - mnew);
                    pk.x = (uint)f2bs(e0) | ((uint)f2bs(e1) << 16);
                    pk.y = (uint)f2bs(e2) | ((uint)f2bs(e3) << 16);
                }
                *(uint2*)&Plds[w][l16][c * 16 + quad * 4] = pk;
            }

            // alpha: QK layout (row=l16, lanes 0..15) -> PV layout
            // (row=quad*4+r)
            float alo[4];
            #pragma unroll
            for (int r = 0; r < 4; r++) alo[r] = __shfl(al, quad * 4 + r);
            #pragma unroll
            for (int f = 0; f < 4; f++)
                #pragma unroll
                for (int r = 0; r < 4; r++) o[f][r] *= alo[r];
            #pragma unroll
            for (int r = 0; r < 4; r++) o4[r] *= alo[r];

            // PV (+ ones-column row-sum into o4). Same-wave P RAW ordered
            // by compiler lgkmcnt (wave-private Plds slice).
            #pragma unroll
            for (int kg = 0; kg < 4; kg++) {
                short8 pa = *(const short8*)&Plds[w][l16][kg * 32 + quad * 8];
                #pragma unroll
                for (int f = 0; f < 4; f++) {
                    short8 vb = *(const short8*)&Vlds[f * 16 + l16][kg * 32 + quad * 8];
                    o[f] = __builtin_amdgcn_mfma_f32_16x16x32_bf16(pa, vb, o[f], 0, 0, 0);
                }
                o4 = __builtin_amdgcn_mfma_f32_16x16x32_bf16(pa, vone, o4, 0, 0, 0);
            }
        }
    }

    #pragma unroll
    for (int r = 0; r < 4; r++) {
        const float linv = 1.f / o4[r];
        bf16* op = outp + (size_t)(b * T_ + qbase + quad * 4 + r) * E_ + h * HS_;
        #pragma unroll
        for (int f = 0; f < 4; f++)
            op[f * 16 + l16] = f2b(o[f][r] * linv);
    }
}

// ---------------------------------------------------------------------------
// LayerNorm(a + r)*g + be. One row (E=1024) per block.
// G13: each thread owns 4 CONSECUTIVE elements -> ushort4/float4 vector
// loads and stores.
// ---------------------------------------------------------------------------
template <typename TA, typename TR, typename TO>
__global__ __launch_bounds__(256) void ln_kernel(const TA* a,
                                                 const TR* r,
                                                 const float* g,
                                                 const float* be,
                                                 TO* out)
{
    const int row = blockIdx.x;
    const int c0  = (int)threadIdx.x * 4;
    const TA* pa = a + (size_t)row * E_ + c0;
    const TR* pr = r + (size_t)row * E_ + c0;
    TO* po = out + (size_t)row * E_ + c0;

    float va[4], vr[4], v[4];
    ld4(pa, va);
    ld4(pr, vr);
    float sum = 0.f, sq = 0.f;
    #pragma unroll
    for (int j = 0; j < 4; j++) {
        v[j] = va[j] + vr[j];
        sum += v[j];
        sq  += v[j] * v[j];
    }
    #pragma unroll
    for (int o = 32; o >= 1; o >>= 1) {
        sum += __shfl_xor(sum, o);
        sq  += __shfl_xor(sq, o);
    }
    __shared__ float red[8];
    const int wave = threadIdx.x >> 6, lane = threadIdx.x & 63;
    if (lane == 0) { red[wave] = sum; red[4 + wave] = sq; }
    __syncthreads();
    sum = red[0] + red[1] + red[2] + red[3];
    sq  = red[4] + red[5] + red[6] + red[7];

    const float mu  = sum * (1.f / E_);
    const float var = fmaxf(sq * (1.f / E_) - mu * mu, 0.f);
    const float rs  = rsqrtf(var + EPS_);

    const float4 gv = *(const float4*)(g + c0);
    const float4 bv = *(const float4*)(be + c0);
    float ov[4];
    ov[0] = (v[0] - mu) * rs * gv.x + bv.x;
    ov[1] = (v[1] - mu) * rs * gv.y + bv.y;
    ov[2] = (v[2] - mu) * rs * gv.z + bv.z;
    ov[3] = (v[3] - mu) * rs * gv.w + bv.w;
    st4(po, ov);
}

// ---------------------------------------------------------------------------
// ws plan (peak 32 MiB). d_out (16 MB fp32) is scratch until the end:
//   prepA:  xb @ d_out[0..8M); WqkvT ws[0..6M); WoT ws[30..32M)
//   qkv GEMM (VSPLIT): qkv Q/K -> ws[6..30M); V -> vT @ d_out[8..16M)
//   attn:   reads qkv + vT, writes attnout @ d_out[0..8M)  (xb dead)
//   prep2:  W1T ws[0..8M); W2T ws[8..16M)   (WqkvT dead after qkv;
//           qkv dead after attn)
//   proj    ws[16..24M); y ws[24..32M) (WoT dead after Wo-GEMM)
//   FFN (column-split): per half c0 in {0, 2048}:
//     h_half = relu(y @ W1T[c0:c0+2048]) [4096,2048] bf16 -> d_out[0..16M)
//       (attnout dead after proj, vT dead after attn)
//     ff (+)= h_half @ W2[c0:c0+2048,:]  [4096,1024] bf16 -> ws[16..24M)
//   LN2: reads y + ff from ws, writes fp32 to d_out. No aliasing.
// ---------------------------------------------------------------------------
extern "C" void kernel_launch(void* const* d_in, const int* in_sizes, int n_in,
                              void* d_out, int out_size, void* d_ws, size_t ws_size,
                              hipStream_t stream)
{
    (void)in_sizes; (void)n_in; (void)out_size; (void)ws_size;
    const float* x   = (const float*)d_in[0];
    const float* Wq  = (const float*)d_in[1];
    const float* Wk  = (const float*)d_in[2];
    const float* Wv  = (const float*)d_in[3];
    const float* Wo  = (const float*)d_in[4];
    const float* bo  = (const float*)d_in[5];
    const float* W1  = (const float*)d_in[6];
    const float* b1  = (const float*)d_in[7];
    const float* W2  = (const float*)d_in[8];
    const float* b2  = (const float*)d_in[9];
    const float* g1  = (const float*)d_in[10];
    const float* be1 = (const float*)d_in[11];
    const float* g2  = (const float*)d_in[12];
    const float* be2 = (const float*)d_in[13];

    const int M = B_ * T_;   // 4096
    char* ws = (char*)d_ws;
    bf16* WqkvT = (bf16*)(ws);                      // 0..6M
    bf16* qkv   = (bf16*)(ws + (size_t)6291456);    // 6..30M
    bf16* WoT   = (bf16*)(ws + (size_t)31457280);   // 30..32M
    bf16* W1T   = (bf16*)(ws);                      // 0..8M   (post-attn)
    bf16* W2T   = (bf16*)(ws + (size_t)8388608);    // 8..16M  (post-attn)
    bf16* proj  = (bf16*)(ws + (size_t)16777216);   // 16..24M
    bf16* y     = (bf16*)(ws + (size_t)25165824);   // 24..32M
    bf16* ff    = (bf16*)(ws + (size_t)16777216);   // 16..24M (proj dead)

    bf16*  xb      = (bf16*)d_out;                            // 0..8M of d_out
    bf16*  vT      = (bf16*)((char*)d_out + (size_t)8388608); // 8..16M of d_out
    bf16*  attnout = (bf16*)d_out;                            // 0..8M (xb dead)
    bf16*  hbuf    = (bf16*)d_out;                            // 0..16M (FFN)
    float* outf    = (float*)d_out;

    // 1) merged prep A: x->bf16, Wqkv^T, Wo^T
    prep_kernel<<<3072, 256, 0, stream>>>(x, (ushort*)xb, Wq, Wk, Wv, WqkvT, Wo, WoT);

    // 2) qkv = xb @ WqkvT^T  [4096,3072], K=1024  (768 blocks, 128x128, BK=64)
    //    VSPLIT: V-projection tiles write vT directly (vt_transpose fused).
    gemm_bt<2, 2, 4, 4, 2, false, false, false, true, bf16><<<dim3(24, 32), 256, 0, stream>>>(
        xb, WqkvT, nullptr, qkv, vT, M, 3 * E_, E_, E_);

    // 3) flash attention -> attnout (1024 blocks, XCD-pinned, heavy-first)
    attn_mfma<<<dim3(32, 32), 256, 0, stream>>>(qkv, vT, attnout);

    // 4) merged prep B: W1^T, W2^T (qkv dead)
    prep2_kernel<<<2048, 256, 0, stream>>>(W1, W1T, W2, W2T);

    // 5) proj = attnout @ WoT^T + bo  (128x64 tiles, BK=64, 512 blocks)
    gemm_bt<2, 2, 4, 2, 2, true, false, false, false, bf16><<<dim3(16, 32), 256, 0, stream>>>(
        attnout, WoT, bo, proj, nullptr, M, E_, E_, E_);

    // 6) y = LN1(x + proj) -> ws[24..32M)
    ln_kernel<float, bf16, bf16><<<M, 256, 0, stream>>>(x, proj, g1, be1, y);

    // 7) FFN column-split: full-M GEMMs, ff accumulated across column halves.
    for (int half = 0; half < 2; half++) {
        const size_t c0 = (size_t)half * 2048;   // h-column block
        // h_half = relu(y @ W1T[c0:c0+2048]^T + b1[c0:]) : [4096,2048]
        // 128x128 tiles -> dim3(16,32) = 512 blocks
        gemm_bt<2, 2, 4, 4, 2, true, true, false, false, bf16><<<dim3(16, 32), 256, 0, stream>>>(
            y, W1T + c0 * E_, b1 + c0, hbuf, nullptr, M, 2048, E_, E_);
        // ff (+)= h_half @ W2[c0:c0+2048,:] : [4096,1024], K=2048
        // 128x64 tiles -> dim3(16,32) = 512 blocks, 2 blocks/CU
        // (r10: 64x64 tiles ran at ~64^2-class TF ~ 343; 128x64 is the
        //  proj-verified config with 2x better MFMA:ds_read ratio)
        if (half == 0)
            gemm_bt<2, 2, 4, 2, 2, true, false, false, false, bf16><<<dim3(16, 32), 256, 0, stream>>>(
                hbuf, W2T + c0, b2, ff, nullptr, M, E_, 2048, 4 * E_);
        else
            gemm_bt<2, 2, 4, 2, 2, false, false, true, false, bf16><<<dim3(16, 32), 256, 0, stream>>>(
                hbuf, W2T + c0, nullptr, ff, nullptr, M, E_, 2048, 4 * E_);
    }

    // 8) out = LN2(y + ff) -> d_out fp32 (sources in ws, no aliasing)
    ln_kernel<bf16, bf16, float><<<M, 256, 0, stream>>>(y, ff, g2, be2, outf);
}

// Round 13
// 365.666 us; speedup vs baseline: 1.0369x; 1.0369x over previous
//
#include <hip/hip_runtime.h>
#include <hip/hip_bf16.h>
#include <cstdint>
#include <cstddef>

typedef __hip_bfloat16 bf16;
typedef __attribute__((ext_vector_type(8))) short short8;
typedef __attribute__((ext_vector_type(4))) float f32x4;

#define B_  2
#define T_  2048
#define E_  1024
#define H_  16
#define HS_ 64
#define EPS_ 1e-5f
#define NEG_BIG -1.0e30f
// 0.125 (1/sqrt(64)) * log2(e): scores in exp2 domain
#define SCL2E 0.18033688011112042f

__device__ __forceinline__ float b2f(bf16 v) { return __bfloat162float(v); }
__device__ __forceinline__ bf16  f2b(float v) { return __float2bfloat16(v); }
__device__ __forceinline__ ushort f2bs(float v) { bf16 b = __float2bfloat16(v); return *(ushort*)&b; }
__device__ __forceinline__ float ld1(const bf16* p) { return b2f(*p); }
__device__ __forceinline__ float ld1(const float* p) { return *p; }
__device__ __forceinline__ void st1(bf16* p, float v) { *p = f2b(v); }
__device__ __forceinline__ void st1(float* p, float v) { *p = v; }

// vectorized 4-elem load/store helpers (G13: no scalar bf16 loads)
__device__ __forceinline__ void ld4(const bf16* p, float v[4]) {
    ushort4 u = *(const ushort4*)p;
    v[0] = b2f(*(const bf16*)&u.x);
    v[1] = b2f(*(const bf16*)&u.y);
    v[2] = b2f(*(const bf16*)&u.z);
    v[3] = b2f(*(const bf16*)&u.w);
}
__device__ __forceinline__ void ld4(const float* p, float v[4]) {
    float4 f = *(const float4*)p;
    v[0] = f.x; v[1] = f.y; v[2] = f.z; v[3] = f.w;
}
__device__ __forceinline__ void st4(bf16* p, const float v[4]) {
    ushort4 u;
    u.x = f2bs(v[0]); u.y = f2bs(v[1]); u.z = f2bs(v[2]); u.w = f2bs(v[3]);
    *(ushort4*)p = u;
}
__device__ __forceinline__ void st4(float* p, const float v[4]) {
    float4 f; f.x = v[0]; f.y = v[1]; f.z = v[2]; f.w = v[3];
    *(float4*)p = f;
}

__device__ __forceinline__ float fexp2(float x) {
#if __has_builtin(__builtin_amdgcn_exp2f)
    return __builtin_amdgcn_exp2f(x);
#else
    return exp2f(x);
#endif
}

// async global->LDS, 16B per lane; lds dest = wave-uniform base + lane*16
__device__ __forceinline__ void gload16(const void* g, const void* l) {
    __builtin_amdgcn_global_load_lds(
        (const __attribute__((address_space(1))) unsigned int*)(size_t)g,
        (__attribute__((address_space(3))) unsigned int*)(unsigned int)(size_t)l,
        16, 0, 0);
}

// ---------------------------------------------------------------------------
// 64x64 fp32->bf16 transpose tile (shared buffer passed in)
// ---------------------------------------------------------------------------
__device__ __forceinline__ void transpose_tile_s(short t[64][72],
                                                 const float* in, size_t ldin,
                                                 bf16* out, size_t ldout,
                                                 int r0, int c0)
{
    const int tid = threadIdx.x;
    const int tr = tid >> 2, tc4 = (tid & 3) * 16;

    const float* p = in + (size_t)(r0 + tr) * ldin + c0 + tc4;
    float4 v0 = ((const float4*)p)[0], v1 = ((const float4*)p)[1];
    float4 v2 = ((const float4*)p)[2], v3 = ((const float4*)p)[3];
    union { ushort u[16]; uint4 q[2]; } pk;
    pk.u[0] = f2bs(v0.x); pk.u[1] = f2bs(v0.y); pk.u[2]  = f2bs(v0.z); pk.u[3]  = f2bs(v0.w);
    pk.u[4] = f2bs(v1.x); pk.u[5] = f2bs(v1.y); pk.u[6]  = f2bs(v1.z); pk.u[7]  = f2bs(v1.w);
    pk.u[8] = f2bs(v2.x); pk.u[9] = f2bs(v2.y); pk.u[10] = f2bs(v2.z); pk.u[11] = f2bs(v2.w);
    pk.u[12] = f2bs(v3.x); pk.u[13] = f2bs(v3.y); pk.u[14] = f2bs(v3.z); pk.u[15] = f2bs(v3.w);
    *(uint4*)&t[tr][tc4]     = pk.q[0];
    *(uint4*)&t[tr][tc4 + 8] = pk.q[1];
    __syncthreads();

    const int tcI = tid >> 2, rj = (tid & 3) * 16;
    union { ushort u[16]; uint4 q[2]; } po;
    #pragma unroll
    for (int j = 0; j < 16; j++) po.u[j] = (ushort)t[rj + j][tcI];
    bf16* op = out + (size_t)(c0 + tcI) * ldout + r0 + rj;
    ((uint4*)op)[0] = po.q[0];
    ((uint4*)op)[1] = po.q[1];
}

// ---------------------------------------------------------------------------
// Merged prep A: x->bf16 (2048 blocks) + Wqkv^T (768) + Wo^T (256)
// ---------------------------------------------------------------------------
__global__ __launch_bounds__(256) void prep_kernel(const float* __restrict__ x,
                                                   ushort* __restrict__ xb,
                                                   const float* __restrict__ Wq,
                                                   const float* __restrict__ Wk,
                                                   const float* __restrict__ Wv,
                                                   bf16* __restrict__ WqkvT,
                                                   const float* __restrict__ Wo,
                                                   bf16* __restrict__ WoT)
{
    __shared__ short t[64][72];
    const int bid = blockIdx.x;
    if (bid < 2048) {
        int i = (bid * 256 + (int)threadIdx.x) * 8;
        float4 a = ((const float4*)(x + i))[0];
        float4 b = ((const float4*)(x + i))[1];
        union { ushort u[8]; uint4 v; } p;
        p.u[0] = f2bs(a.x); p.u[1] = f2bs(a.y); p.u[2] = f2bs(a.z); p.u[3] = f2bs(a.w);
        p.u[4] = f2bs(b.x); p.u[5] = f2bs(b.y); p.u[6] = f2bs(b.z); p.u[7] = f2bs(b.w);
        *(uint4*)(xb + i) = p.v;
    } else if (bid < 2048 + 768) {
        const int i = bid - 2048;            // (s 0..47) x (xt 0..15)
        const int s = i >> 4, xt = i & 15;
        const int proj = s >> 4, h = s & 15;
        const float* W = (proj == 0) ? Wq : ((proj == 1) ? Wk : Wv);
        transpose_tile_s(t, W + (size_t)h * E_ * HS_, HS_,
                         WqkvT + ((size_t)proj * E_ + h * 64) * E_, E_,
                         xt * 64, 0);
    } else {
        const int i = bid - 2816;            // 256 tiles of Wo [1024][1024]
        transpose_tile_s(t, Wo, E_, WoT, E_, (i >> 4) * 64, (i & 15) * 64);
    }
}

// ---------------------------------------------------------------------------
// Merged prep B: W1^T (1024 blocks) + W2^T (1024 blocks)
// ---------------------------------------------------------------------------
__global__ __launch_bounds__(256) void prep2_kernel(const float* __restrict__ W1,
                                                    bf16* __restrict__ W1T,
                                                    const float* __restrict__ W2,
                                                    bf16* __restrict__ W2T)
{
    __shared__ short t[64][72];
    const int bid = blockIdx.x;
    if (bid < 1024) {   // W1 [1024][4096] -> W1T [4096][1024]
        transpose_tile_s(t, W1, 4 * E_, W1T, E_,
                         (bid & 15) * 64, (bid >> 4) * 64);
    } else {            // W2 [4096][1024] -> W2T [1024][4096]
        const int i = bid - 1024;
        transpose_tile_s(t, W2, E_, W2T, 4 * E_,
                         (i >> 4) * 64, (i & 15) * 64);
    }
}

// ---------------------------------------------------------------------------
// MFMA GEMM: C[M,N] = A[M,K] @ BT[N,K]^T (+bias fp32)(+relu)(+C-accumulate),
// bf16 in, TO out. BT row stride = ldb (>= K; enables K-sliced B operands).
// XCD-pinned bijective grid remap (requires gridDim.x % 8 == 0).
// KS selects BK = 32*KS: KS=4 (BK=128) halves the barrier-stage count for
// K-heavy calls whose grids are already at/below the BK=128 LDS occupancy
// cap (proj/W1/W2: 2 blocks/CU either way). qkv keeps KS=2 (768-block grid
// wants 3/CU; 64KB LDS would cap it at 2 — the m132 trap).
// VSPLIT (qkv call only): blocks with col0 >= 2048 hold the V-projection;
// they write vT [bh][64][T] directly (transposed) instead of C.
// ---------------------------------------------------------------------------
template <int WROWS, int WCOLS, int MF, int NF, int KS, bool BIAS, bool RELU,
          bool ACC, bool VSPLIT, typename TO>
__global__ __launch_bounds__(256) void gemm_bt(const bf16* __restrict__ A,
                                               const bf16* __restrict__ BT,
                                               const float* __restrict__ bias,
                                               TO* __restrict__ C,
                                               bf16* __restrict__ vTout,
                                               int M, int N, int K, int ldb)
{
    constexpr int BM = WROWS * MF * 16;
    constexpr int BN = WCOLS * NF * 16;
    __shared__ short Asm[KS][BM][32];
    __shared__ short Bsm[KS][BN][32];

    const int tid  = threadIdx.x;
    const int wv   = tid >> 6, lane = tid & 63;
    const int quad = lane >> 4, l16 = lane & 15;

    // XCD-pinned bijective remap (gx % 8 == 0 at every call site)
    const int gx = gridDim.x;
    const int p  = blockIdx.y * gx + blockIdx.x;
    const int spx = gx >> 3;                 // column strips per XCD
    const int xcd = p & 7, j = p >> 3;
    const int bx = xcd * spx + (j % spx);
    const int by = j / spx;

    const int row0 = by * BM, col0 = bx * BN;
    const int mr0  = (wv / WCOLS) * MF * 16;
    const int nc0  = (wv % WCOLS) * NF * 16;

    const int sr = tid >> 2, sc = tid & 3;
    const bf16* Ag = A  + (size_t)(row0 + sr) * K + sc * 8;
    const bf16* Bg = BT + (size_t)(col0 + (sr % BN)) * ldb + sc * 8;

    f32x4 acc[MF][NF];
    #pragma unroll
    for (int i = 0; i < MF; i++)
        #pragma unroll
        for (int j2 = 0; j2 < NF; j2++) acc[i][j2] = (f32x4){0.f, 0.f, 0.f, 0.f};

    for (int kt = 0; kt < K; kt += 32 * KS) {
        __syncthreads();
        #pragma unroll
        for (int g = 0; g < KS; g++) {
            #pragma unroll
            for (int l = 0; l < BM / 64; l++)
                gload16(Ag + g * 32 + (size_t)l * 64 * K, &Asm[g][l * 64 + wv * 16][0]);
            #pragma unroll
            for (int l = 0; l < BN / 64; l++)
                gload16(Bg + g * 32 + (size_t)l * 64 * ldb, &Bsm[g][l * 64 + wv * 16][0]);
        }
        Ag += 32 * KS; Bg += 32 * KS;
        __syncthreads();

        #pragma unroll
        for (int g = 0; g < KS; g++) {
            short8 af[MF], bfr[NF];
            #pragma unroll
            for (int mf = 0; mf < MF; mf++)
                af[mf] = *(const short8*)&Asm[g][mr0 + mf * 16 + l16][quad * 8];
            #pragma unroll
            for (int nf = 0; nf < NF; nf++)
                bfr[nf] = *(const short8*)&Bsm[g][nc0 + nf * 16 + l16][quad * 8];
            #pragma unroll
            for (int mf = 0; mf < MF; mf++)
                #pragma unroll
                for (int nf = 0; nf < NF; nf++)
                    acc[mf][nf] = __builtin_amdgcn_mfma_f32_16x16x32_bf16(
                        af[mf], bfr[nf], acc[mf][nf], 0, 0, 0);
        }
    }

    if (VSPLIT && col0 >= 2 * E_) {
        // V-projection tile -> write vT [bh][64][T] transposed.
        #pragma unroll
        for (int nf = 0; nf < NF; nf++) {
            const int cv = col0 + nc0 + nf * 16 + l16 - 2 * E_;
            const int hh = cv >> 6, dd = cv & 63;
            #pragma unroll
            for (int mf = 0; mf < MF; mf++) {
                const int row = row0 + mr0 + mf * 16 + quad * 4;
                const int bb = row >> 11, tt = row & (T_ - 1);
                ushort4 u;
                u.x = f2bs(acc[mf][nf][0]);
                u.y = f2bs(acc[mf][nf][1]);
                u.z = f2bs(acc[mf][nf][2]);
                u.w = f2bs(acc[mf][nf][3]);
                *(ushort4*)(vTout + ((size_t)(bb * H_ + hh) * 64 + dd) * T_ + tt) = u;
            }
        }
    } else {
        #pragma unroll
        for (int nf = 0; nf < NF; nf++) {
            const int col = col0 + nc0 + nf * 16 + l16;
            const float bv = BIAS ? bias[col] : 0.f;
            #pragma unroll
            for (int mf = 0; mf < MF; mf++) {
                #pragma unroll
                for (int r = 0; r < 4; r++) {
                    const int row = row0 + mr0 + mf * 16 + quad * 4 + r;
                    float v = acc[mf][nf][r] + bv;
                    if (ACC) v += ld1(&C[(size_t)row * N + col]);
                    if (RELU) v = fmaxf(v, 0.f);
                    st1(&C[(size_t)row * N + col], v);
                }
            }
        }
    }
}

// ---------------------------------------------------------------------------
// Flash attention (best measured config, 58 us): 128-key stages, no setprio,
// unpaired 1024-block grid, XCD-pinned (bh by p%8), heavy-first tiles,
// direct global->LDS staging (no reg arrays across barriers), swapped-QK
// lane-local softmax, ones-column denominator, exp2 domain.
// ---------------------------------------------------------------------------
__global__ __launch_bounds__(256) void attn_mfma(const bf16* __restrict__ qkv,
                                                 const bf16* __restrict__ vT,
                                                 bf16* __restrict__ outp)
{
    __shared__ short Klds[128][72];
    __shared__ short Vlds[64][136];
    __shared__ short Plds[4][16][136];

    const int tid  = threadIdx.x;
    const int w    = tid >> 6, lane = tid & 63;
    const int quad = lane >> 4, l16 = lane & 15;

    const int p    = blockIdx.y * 32 + blockIdx.x;   // 1024 blocks
    const int bh   = (p & 7) * 4 + ((p >> 3) & 3);   // XCD-pinned by p%8
    const int tile = 31 - (p >> 5);                  // heavy-first
    const int b    = bh >> 4, h = bh & 15;
    const size_t rowb = (size_t)b * T_ * 3 * E_;
    const int t0    = tile * 64;
    const int qbase = t0 + w * 16;

    // K staging map: key = tid>>1 (0..127), d-half = (tid&1)*32
    const int kkey = tid >> 1, kdh = (tid & 1) * 32;
    const bf16* Kg = qkv + rowb + E_ + h * HS_ + kdh;
    // V staging map: d = tid>>2 (0..63), key-seg = (tid&3)*32
    const int vd = tid >> 2, vseg = (tid & 3) * 32;
    const bf16* Vg = vT + ((size_t)bh * 64 + vd) * T_ + vseg;

    short8 vone;
    #pragma unroll
    for (int j = 0; j < 8; j++) vone[j] = (short)0x3F80;   // bf16 1.0

    const bf16* Qp = qkv + rowb + (size_t)(qbase + l16) * (3 * E_) + h * HS_;
    const short8 aq0 = *(const short8*)(Qp + quad * 8);
    const short8 aq1 = *(const short8*)(Qp + 32 + quad * 8);

    f32x4 o[4], o4;
    #pragma unroll
    for (int f = 0; f < 4; f++) o[f] = (f32x4){0.f, 0.f, 0.f, 0.f};
    o4 = (f32x4){0.f, 0.f, 0.f, 0.f};
    float mrow = NEG_BIG;

    for (int kt0 = 0; kt0 <= t0; kt0 += 128) {
        __syncthreads();   // all reads of prev K/Vlds done
        {
            // DIRECT load->LDS staging: transient regs only,
            // no named arrays living across a barrier.
            const int kr = (kt0 + kkey < T_) ? kt0 + kkey : T_ - 1;
            const bf16* kp = Kg + (size_t)kr * (3 * E_);
            *(uint4*)&Klds[kkey][kdh]      = ((const uint4*)kp)[0];
            *(uint4*)&Klds[kkey][kdh + 8]  = ((const uint4*)kp)[1];
            *(uint4*)&Klds[kkey][kdh + 16] = ((const uint4*)kp)[2];
            *(uint4*)&Klds[kkey][kdh + 24] = ((const uint4*)kp)[3];
            const bf16* vp = Vg + kt0;
            *(uint4*)&Vlds[vd][vseg]       = ((const uint4*)vp)[0];
            *(uint4*)&Vlds[vd][vseg + 8]   = ((const uint4*)vp)[1];
            *(uint4*)&Vlds[vd][vseg + 16]  = ((const uint4*)vp)[2];
            *(uint4*)&Vlds[vd][vseg + 24]  = ((const uint4*)vp)[3];
        }
        __syncthreads();   // staging visible

        const bool active = (kt0 <= qbase + 15);       // wave-uniform
        const int nv0 = ((qbase + 15 - kt0) >> 4) + 1; // valid chunks
        const int nvalid = active ? (nv0 < 8 ? nv0 : 8) : 0;

        // swapped QK^T: ps[c][r] = S[qrow=qbase+l16][key=kt0+c*16+quad*4+r]
        float ps[8][4];
        #pragma unroll
        for (int c = 0; c < 8; c++) {
            if (c < nvalid) {
                const int kc = kt0 + c * 16;
                const int krow = c * 16 + l16;
                short8 bk0 = *(const short8*)&Klds[krow][quad * 8];
                short8 bk1 = *(const short8*)&Klds[krow][32 + quad * 8];
                f32x4 s = (f32x4){0.f, 0.f, 0.f, 0.f};
                s = __builtin_amdgcn_mfma_f32_16x16x32_bf16(bk0, aq0, s, 0, 0, 0);
                s = __builtin_amdgcn_mfma_f32_16x16x32_bf16(bk1, aq1, s, 0, 0, 0);
                const bool needmask = (kc + 15 > qbase);   // wave-uniform
                #pragma unroll
                for (int r = 0; r < 4; r++) {
                    float sv = s[r] * SCL2E;
                    if (needmask && (kc + quad * 4 + r > qbase + l16)) sv = NEG_BIG;
                    ps[c][r] = sv;
                }
            }
        }
        if (active) {
            // lane-local max (lane's own keys) + cross-quad combine:
            // after 2 shfl, every lane holds the full max of q-row l16.
            float mx = ps[0][0];
            #pragma unroll
            for (int r = 1; r < 4; r++) mx = fmaxf(mx, ps[0][r]);
            #pragma unroll
            for (int c = 1; c < 8; c++)
                if (c < nvalid)
                    #pragma unroll
                    for (int r = 0; r < 4; r++) mx = fmaxf(mx, ps[c][r]);
            mx = fmaxf(mx, __shfl_xor(mx, 16));
            mx = fmaxf(mx, __shfl_xor(mx, 32));
            const float mnew = fmaxf(mrow, mx);
            const float al = fexp2(mrow - mnew);
            mrow = mnew;

            // P = exp2(s - m); 4 consecutive keys -> one b64 LDS write
            #pragma unroll
            for (int c = 0; c < 8; c++) {
                uint2 pk; pk.x = 0u; pk.y = 0u;
                if (c < nvalid) {
                    const float e0 = fexp2(ps[c][0] - mnew);
                    const float e1 = fexp2(ps[c][1] - mnew);
                    const float e2 = fexp2(ps[c][2] - mnew);
                    const float e3 = fexp2(ps[c][3] - mnew);
                    pk.x = (uint)f2bs(e0) | ((uint)f2bs(e1) << 16);
                    pk.y = (uint)f2bs(e2) | ((uint)f2bs(e3) << 16);
                }
                *(uint2*)&Plds[w][l16][c * 16 + quad * 4] = pk;
            }

            // alpha: QK layout (row=l16, lanes 0..15) -> PV layout
            // (row=quad*4+r)
            float alo[4];
            #pragma unroll
            for (int r = 0; r < 4; r++) alo[r] = __shfl(al, quad * 4 + r);
            #pragma unroll
            for (int f = 0; f < 4; f++)
                #pragma unroll
                for (int r = 0; r < 4; r++) o[f][r] *= alo[r];
            #pragma unroll
            for (int r = 0; r < 4; r++) o4[r] *= alo[r];

            // PV (+ ones-column row-sum into o4). Same-wave P RAW ordered
            // by compiler lgkmcnt (wave-private Plds slice).
            #pragma unroll
            for (int kg = 0; kg < 4; kg++) {
                short8 pa = *(const short8*)&Plds[w][l16][kg * 32 + quad * 8];
                #pragma unroll
                for (int f = 0; f < 4; f++) {
                    short8 vb = *(const short8*)&Vlds[f * 16 + l16][kg * 32 + quad * 8];
                    o[f] = __builtin_amdgcn_mfma_f32_16x16x32_bf16(pa, vb, o[f], 0, 0, 0);
                }
                o4 = __builtin_amdgcn_mfma_f32_16x16x32_bf16(pa, vone, o4, 0, 0, 0);
            }
        }
    }

    #pragma unroll
    for (int r = 0; r < 4; r++) {
        const float linv = 1.f / o4[r];
        bf16* op = outp + (size_t)(b * T_ + qbase + quad * 4 + r) * E_ + h * HS_;
        #pragma unroll
        for (int f = 0; f < 4; f++)
            op[f * 16 + l16] = f2b(o[f][r] * linv);
    }
}

// ---------------------------------------------------------------------------
// LayerNorm(a + r)*g + be. One row (E=1024) per block.
// G13: each thread owns 4 CONSECUTIVE elements -> ushort4/float4 vector
// loads and stores.
// ---------------------------------------------------------------------------
template <typename TA, typename TR, typename TO>
__global__ __launch_bounds__(256) void ln_kernel(const TA* a,
                                                 const TR* r,
                                                 const float* g,
                                                 const float* be,
                                                 TO* out)
{
    const int row = blockIdx.x;
    const int c0  = (int)threadIdx.x * 4;
    const TA* pa = a + (size_t)row * E_ + c0;
    const TR* pr = r + (size_t)row * E_ + c0;
    TO* po = out + (size_t)row * E_ + c0;

    float va[4], vr[4], v[4];
    ld4(pa, va);
    ld4(pr, vr);
    float sum = 0.f, sq = 0.f;
    #pragma unroll
    for (int j = 0; j < 4; j++) {
        v[j] = va[j] + vr[j];
        sum += v[j];
        sq  += v[j] * v[j];
    }
    #pragma unroll
    for (int o = 32; o >= 1; o >>= 1) {
        sum += __shfl_xor(sum, o);
        sq  += __shfl_xor(sq, o);
    }
    __shared__ float red[8];
    const int wave = threadIdx.x >> 6, lane = threadIdx.x & 63;
    if (lane == 0) { red[wave] = sum; red[4 + wave] = sq; }
    __syncthreads();
    sum = red[0] + red[1] + red[2] + red[3];
    sq  = red[4] + red[5] + red[6] + red[7];

    const float mu  = sum * (1.f / E_);
    const float var = fmaxf(sq * (1.f / E_) - mu * mu, 0.f);
    const float rs  = rsqrtf(var + EPS_);

    const float4 gv = *(const float4*)(g + c0);
    const float4 bv = *(const float4*)(be + c0);
    float ov[4];
    ov[0] = (v[0] - mu) * rs * gv.x + bv.x;
    ov[1] = (v[1] - mu) * rs * gv.y + bv.y;
    ov[2] = (v[2] - mu) * rs * gv.z + bv.z;
    ov[3] = (v[3] - mu) * rs * gv.w + bv.w;
    st4(po, ov);
}

// ---------------------------------------------------------------------------
// ws plan (peak 32 MiB). d_out (16 MB fp32) is scratch until the end:
//   prepA:  xb @ d_out[0..8M); WqkvT ws[0..6M); WoT ws[30..32M)
//   qkv GEMM (VSPLIT): qkv Q/K -> ws[6..30M); V -> vT @ d_out[8..16M)
//   attn:   reads qkv + vT, writes attnout @ d_out[0..8M)  (xb dead)
//   prep2:  W1T ws[0..8M); W2T ws[8..16M)   (WqkvT dead after qkv;
//           qkv dead after attn)
//   proj    ws[16..24M); y ws[24..32M) (WoT dead after Wo-GEMM)
//   FFN (column-split): per half c0 in {0, 2048}:
//     h_half = relu(y @ W1T[c0:c0+2048]) [4096,2048] bf16 -> d_out[0..16M)
//       (attnout dead after proj, vT dead after attn)
//     ff (+)= h_half @ W2[c0:c0+2048,:]  [4096,1024] bf16 -> ws[16..24M)
//   LN2: reads y + ff from ws, writes fp32 to d_out. No aliasing.
// ---------------------------------------------------------------------------
extern "C" void kernel_launch(void* const* d_in, const int* in_sizes, int n_in,
                              void* d_out, int out_size, void* d_ws, size_t ws_size,
                              hipStream_t stream)
{
    (void)in_sizes; (void)n_in; (void)out_size; (void)ws_size;
    const float* x   = (const float*)d_in[0];
    const float* Wq  = (const float*)d_in[1];
    const float* Wk  = (const float*)d_in[2];
    const float* Wv  = (const float*)d_in[3];
    const float* Wo  = (const float*)d_in[4];
    const float* bo  = (const float*)d_in[5];
    const float* W1  = (const float*)d_in[6];
    const float* b1  = (const float*)d_in[7];
    const float* W2  = (const float*)d_in[8];
    const float* b2  = (const float*)d_in[9];
    const float* g1  = (const float*)d_in[10];
    const float* be1 = (const float*)d_in[11];
    const float* g2  = (const float*)d_in[12];
    const float* be2 = (const float*)d_in[13];

    const int M = B_ * T_;   // 4096
    char* ws = (char*)d_ws;
    bf16* WqkvT = (bf16*)(ws);                      // 0..6M
    bf16* qkv   = (bf16*)(ws + (size_t)6291456);    // 6..30M
    bf16* WoT   = (bf16*)(ws + (size_t)31457280);   // 30..32M
    bf16* W1T   = (bf16*)(ws);                      // 0..8M   (post-attn)
    bf16* W2T   = (bf16*)(ws + (size_t)8388608);    // 8..16M  (post-attn)
    bf16* proj  = (bf16*)(ws + (size_t)16777216);   // 16..24M
    bf16* y     = (bf16*)(ws + (size_t)25165824);   // 24..32M
    bf16* ff    = (bf16*)(ws + (size_t)16777216);   // 16..24M (proj dead)

    bf16*  xb      = (bf16*)d_out;                            // 0..8M of d_out
    bf16*  vT      = (bf16*)((char*)d_out + (size_t)8388608); // 8..16M of d_out
    bf16*  attnout = (bf16*)d_out;                            // 0..8M (xb dead)
    bf16*  hbuf    = (bf16*)d_out;                            // 0..16M (FFN)
    float* outf    = (float*)d_out;

    // 1) merged prep A: x->bf16, Wqkv^T, Wo^T
    prep_kernel<<<3072, 256, 0, stream>>>(x, (ushort*)xb, Wq, Wk, Wv, WqkvT, Wo, WoT);

    // 2) qkv = xb @ WqkvT^T  [4096,3072], K=1024  (768 blocks, 128x128, BK=64)
    //    VSPLIT: V-projection tiles write vT directly (vt_transpose fused).
    gemm_bt<2, 2, 4, 4, 2, false, false, false, true, bf16><<<dim3(24, 32), 256, 0, stream>>>(
        xb, WqkvT, nullptr, qkv, vT, M, 3 * E_, E_, E_);

    // 3) flash attention -> attnout (1024 blocks, XCD-pinned, heavy-first)
    attn_mfma<<<dim3(32, 32), 256, 0, stream>>>(qkv, vT, attnout);

    // 4) merged prep B: W1^T, W2^T (qkv dead)
    prep2_kernel<<<2048, 256, 0, stream>>>(W1, W1T, W2, W2T);

    // 5) proj = attnout @ WoT^T + bo  (128x64 tiles, BK=128 -> 8 stages)
    gemm_bt<2, 2, 4, 2, 4, true, false, false, false, bf16><<<dim3(16, 32), 256, 0, stream>>>(
        attnout, WoT, bo, proj, nullptr, M, E_, E_, E_);

    // 6) y = LN1(x + proj) -> ws[24..32M)
    ln_kernel<float, bf16, bf16><<<M, 256, 0, stream>>>(x, proj, g1, be1, y);

    // 7) FFN column-split: full-M GEMMs, ff accumulated across column halves.
    for (int half = 0; half < 2; half++) {
        const size_t c0 = (size_t)half * 2048;   // h-column block
        // h_half = relu(y @ W1T[c0:c0+2048]^T + b1[c0:]) : [4096,2048]
        // 128x128 tiles, BK=128 -> 8 stages (LDS 64KB caps 2/CU = grid's 2/CU)
        gemm_bt<2, 2, 4, 4, 4, true, true, false, false, bf16><<<dim3(16, 32), 256, 0, stream>>>(
            y, W1T + c0 * E_, b1 + c0, hbuf, nullptr, M, 2048, E_, E_);
        // ff (+)= h_half @ W2[c0:c0+2048,:] : [4096,1024], K=2048
        // 128x64 tiles, BK=128 -> 16 stages (LDS 48KB, cap 3 >= grid's 2/CU)
        if (half == 0)
            gemm_bt<2, 2, 4, 2, 4, true, false, false, false, bf16><<<dim3(16, 32), 256, 0, stream>>>(
                hbuf, W2T + c0, b2, ff, nullptr, M, E_, 2048, 4 * E_);
        else
            gemm_bt<2, 2, 4, 2, 4, false, false, true, false, bf16><<<dim3(16, 32), 256, 0, stream>>>(
                hbuf, W2T + c0, nullptr, ff, nullptr, M, E_, 2048, 4 * E_);
    }

    // 8) out = LN2(y + ff) -> d_out fp32 (sources in ws, no aliasing)
    ln_kernel<bf16, bf16, float><<<M, 256, 0, stream>>>(y, ff, g2, be2, outf);
}

// Round 14
// 361.925 us; speedup vs baseline: 1.0477x; 1.0103x over previous
//
#include <hip/hip_runtime.h>
#include <hip/hip_bf16.h>
#include <cstdint>
#include <cstddef>

typedef __hip_bfloat16 bf16;
typedef __attribute__((ext_vector_type(8))) short short8;
typedef __attribute__((ext_vector_type(4))) float f32x4;

#define B_  2
#define T_  2048
#define E_  1024
#define H_  16
#define HS_ 64
#define EPS_ 1e-5f
#define NEG_BIG -1.0e30f
// 0.125 (1/sqrt(64)) * log2(e): scores in exp2 domain
#define SCL2E 0.18033688011112042f
// defer-max threshold (log2 units): skip O/o4 rescale while per-stage max
// growth <= 8 -> P bounded by 2^8, bf16-safe; denominators stay consistent.
#define RESCALE_THR 8.0f

__device__ __forceinline__ float b2f(bf16 v) { return __bfloat162float(v); }
__device__ __forceinline__ bf16  f2b(float v) { return __float2bfloat16(v); }
__device__ __forceinline__ ushort f2bs(float v) { bf16 b = __float2bfloat16(v); return *(ushort*)&b; }
__device__ __forceinline__ float ld1(const bf16* p) { return b2f(*p); }
__device__ __forceinline__ float ld1(const float* p) { return *p; }
__device__ __forceinline__ void st1(bf16* p, float v) { *p = f2b(v); }
__device__ __forceinline__ void st1(float* p, float v) { *p = v; }

// vectorized 4-elem load/store helpers (G13: no scalar bf16 loads)
__device__ __forceinline__ void ld4(const bf16* p, float v[4]) {
    ushort4 u = *(const ushort4*)p;
    v[0] = b2f(*(const bf16*)&u.x);
    v[1] = b2f(*(const bf16*)&u.y);
    v[2] = b2f(*(const bf16*)&u.z);
    v[3] = b2f(*(const bf16*)&u.w);
}
__device__ __forceinline__ void ld4(const float* p, float v[4]) {
    float4 f = *(const float4*)p;
    v[0] = f.x; v[1] = f.y; v[2] = f.z; v[3] = f.w;
}
__device__ __forceinline__ void st4(bf16* p, const float v[4]) {
    ushort4 u;
    u.x = f2bs(v[0]); u.y = f2bs(v[1]); u.z = f2bs(v[2]); u.w = f2bs(v[3]);
    *(ushort4*)p = u;
}
__device__ __forceinline__ void st4(float* p, const float v[4]) {
    float4 f; f.x = v[0]; f.y = v[1]; f.z = v[2]; f.w = v[3];
    *(float4*)p = f;
}

__device__ __forceinline__ float fexp2(float x) {
#if __has_builtin(__builtin_amdgcn_exp2f)
    return __builtin_amdgcn_exp2f(x);
#else
    return exp2f(x);
#endif
}

// async global->LDS, 16B per lane; lds dest = wave-uniform base + lane*16
__device__ __forceinline__ void gload16(const void* g, const void* l) {
    __builtin_amdgcn_global_load_lds(
        (const __attribute__((address_space(1))) unsigned int*)(size_t)g,
        (__attribute__((address_space(3))) unsigned int*)(unsigned int)(size_t)l,
        16, 0, 0);
}

// ---------------------------------------------------------------------------
// 64x64 fp32->bf16 transpose tile (shared buffer passed in)
// ---------------------------------------------------------------------------
__device__ __forceinline__ void transpose_tile_s(short t[64][72],
                                                 const float* in, size_t ldin,
                                                 bf16* out, size_t ldout,
                                                 int r0, int c0)
{
    const int tid = threadIdx.x;
    const int tr = tid >> 2, tc4 = (tid & 3) * 16;

    const float* p = in + (size_t)(r0 + tr) * ldin + c0 + tc4;
    float4 v0 = ((const float4*)p)[0], v1 = ((const float4*)p)[1];
    float4 v2 = ((const float4*)p)[2], v3 = ((const float4*)p)[3];
    union { ushort u[16]; uint4 q[2]; } pk;
    pk.u[0] = f2bs(v0.x); pk.u[1] = f2bs(v0.y); pk.u[2]  = f2bs(v0.z); pk.u[3]  = f2bs(v0.w);
    pk.u[4] = f2bs(v1.x); pk.u[5] = f2bs(v1.y); pk.u[6]  = f2bs(v1.z); pk.u[7]  = f2bs(v1.w);
    pk.u[8] = f2bs(v2.x); pk.u[9] = f2bs(v2.y); pk.u[10] = f2bs(v2.z); pk.u[11] = f2bs(v2.w);
    pk.u[12] = f2bs(v3.x); pk.u[13] = f2bs(v3.y); pk.u[14] = f2bs(v3.z); pk.u[15] = f2bs(v3.w);
    *(uint4*)&t[tr][tc4]     = pk.q[0];
    *(uint4*)&t[tr][tc4 + 8] = pk.q[1];
    __syncthreads();

    const int tcI = tid >> 2, rj = (tid & 3) * 16;
    union { ushort u[16]; uint4 q[2]; } po;
    #pragma unroll
    for (int j = 0; j < 16; j++) po.u[j] = (ushort)t[rj + j][tcI];
    bf16* op = out + (size_t)(c0 + tcI) * ldout + r0 + rj;
    ((uint4*)op)[0] = po.q[0];
    ((uint4*)op)[1] = po.q[1];
}

// ---------------------------------------------------------------------------
// Merged prep A: x->bf16 (2048 blocks) + Wqkv^T (768) + Wo^T (256)
// ---------------------------------------------------------------------------
__global__ __launch_bounds__(256) void prep_kernel(const float* __restrict__ x,
                                                   ushort* __restrict__ xb,
                                                   const float* __restrict__ Wq,
                                                   const float* __restrict__ Wk,
                                                   const float* __restrict__ Wv,
                                                   bf16* __restrict__ WqkvT,
                                                   const float* __restrict__ Wo,
                                                   bf16* __restrict__ WoT)
{
    __shared__ short t[64][72];
    const int bid = blockIdx.x;
    if (bid < 2048) {
        int i = (bid * 256 + (int)threadIdx.x) * 8;
        float4 a = ((const float4*)(x + i))[0];
        float4 b = ((const float4*)(x + i))[1];
        union { ushort u[8]; uint4 v; } p;
        p.u[0] = f2bs(a.x); p.u[1] = f2bs(a.y); p.u[2] = f2bs(a.z); p.u[3] = f2bs(a.w);
        p.u[4] = f2bs(b.x); p.u[5] = f2bs(b.y); p.u[6] = f2bs(b.z); p.u[7] = f2bs(b.w);
        *(uint4*)(xb + i) = p.v;
    } else if (bid < 2048 + 768) {
        const int i = bid - 2048;            // (s 0..47) x (xt 0..15)
        const int s = i >> 4, xt = i & 15;
        const int proj = s >> 4, h = s & 15;
        const float* W = (proj == 0) ? Wq : ((proj == 1) ? Wk : Wv);
        transpose_tile_s(t, W + (size_t)h * E_ * HS_, HS_,
                         WqkvT + ((size_t)proj * E_ + h * 64) * E_, E_,
                         xt * 64, 0);
    } else {
        const int i = bid - 2816;            // 256 tiles of Wo [1024][1024]
        transpose_tile_s(t, Wo, E_, WoT, E_, (i >> 4) * 64, (i & 15) * 64);
    }
}

// ---------------------------------------------------------------------------
// Merged prep B: W1^T (1024 blocks) + W2^T (1024 blocks)
// ---------------------------------------------------------------------------
__global__ __launch_bounds__(256) void prep2_kernel(const float* __restrict__ W1,
                                                    bf16* __restrict__ W1T,
                                                    const float* __restrict__ W2,
                                                    bf16* __restrict__ W2T)
{
    __shared__ short t[64][72];
    const int bid = blockIdx.x;
    if (bid < 1024) {   // W1 [1024][4096] -> W1T [4096][1024]
        transpose_tile_s(t, W1, 4 * E_, W1T, E_,
                         (bid & 15) * 64, (bid >> 4) * 64);
    } else {            // W2 [4096][1024] -> W2T [1024][4096]
        const int i = bid - 1024;
        transpose_tile_s(t, W2, E_, W2T, 4 * E_,
                         (i >> 4) * 64, (i & 15) * 64);
    }
}

// ---------------------------------------------------------------------------
// MFMA GEMM: C[M,N] = A[M,K] @ BT[N,K]^T (+bias fp32)(+relu)(+C-accumulate),
// bf16 in, TO out. BT row stride = ldb (>= K; enables K-sliced B operands).
// XCD-pinned bijective grid remap (requires gridDim.x % 8 == 0).
// KS selects BK = 32*KS: KS=4 (BK=128) halves the barrier-stage count for
// K-heavy calls whose grids are already at/below the BK=128 LDS occupancy
// cap (proj/W1/W2: 2 blocks/CU either way; r13 verified -13.5 us). qkv
// keeps KS=2 (768-block grid wants 3/CU; 64KB LDS caps 2 — the m132 trap).
// VSPLIT (qkv call only): blocks with col0 >= 2048 hold the V-projection;
// they write vT [bh][64][T] directly (transposed) instead of C.
// ---------------------------------------------------------------------------
template <int WROWS, int WCOLS, int MF, int NF, int KS, bool BIAS, bool RELU,
          bool ACC, bool VSPLIT, typename TO>
__global__ __launch_bounds__(256) void gemm_bt(const bf16* __restrict__ A,
                                               const bf16* __restrict__ BT,
                                               const float* __restrict__ bias,
                                               TO* __restrict__ C,
                                               bf16* __restrict__ vTout,
                                               int M, int N, int K, int ldb)
{
    constexpr int BM = WROWS * MF * 16;
    constexpr int BN = WCOLS * NF * 16;
    __shared__ short Asm[KS][BM][32];
    __shared__ short Bsm[KS][BN][32];

    const int tid  = threadIdx.x;
    const int wv   = tid >> 6, lane = tid & 63;
    const int quad = lane >> 4, l16 = lane & 15;

    // XCD-pinned bijective remap (gx % 8 == 0 at every call site)
    const int gx = gridDim.x;
    const int p  = blockIdx.y * gx + blockIdx.x;
    const int spx = gx >> 3;                 // column strips per XCD
    const int xcd = p & 7, j = p >> 3;
    const int bx = xcd * spx + (j % spx);
    const int by = j / spx;

    const int row0 = by * BM, col0 = bx * BN;
    const int mr0  = (wv / WCOLS) * MF * 16;
    const int nc0  = (wv % WCOLS) * NF * 16;

    const int sr = tid >> 2, sc = tid & 3;
    const bf16* Ag = A  + (size_t)(row0 + sr) * K + sc * 8;
    const bf16* Bg = BT + (size_t)(col0 + (sr % BN)) * ldb + sc * 8;

    f32x4 acc[MF][NF];
    #pragma unroll
    for (int i = 0; i < MF; i++)
        #pragma unroll
        for (int j2 = 0; j2 < NF; j2++) acc[i][j2] = (f32x4){0.f, 0.f, 0.f, 0.f};

    for (int kt = 0; kt < K; kt += 32 * KS) {
        __syncthreads();
        #pragma unroll
        for (int g = 0; g < KS; g++) {
            #pragma unroll
            for (int l = 0; l < BM / 64; l++)
                gload16(Ag + g * 32 + (size_t)l * 64 * K, &Asm[g][l * 64 + wv * 16][0]);
            #pragma unroll
            for (int l = 0; l < BN / 64; l++)
                gload16(Bg + g * 32 + (size_t)l * 64 * ldb, &Bsm[g][l * 64 + wv * 16][0]);
        }
        Ag += 32 * KS; Bg += 32 * KS;
        __syncthreads();

        #pragma unroll
        for (int g = 0; g < KS; g++) {
            short8 af[MF], bfr[NF];
            #pragma unroll
            for (int mf = 0; mf < MF; mf++)
                af[mf] = *(const short8*)&Asm[g][mr0 + mf * 16 + l16][quad * 8];
            #pragma unroll
            for (int nf = 0; nf < NF; nf++)
                bfr[nf] = *(const short8*)&Bsm[g][nc0 + nf * 16 + l16][quad * 8];
            #pragma unroll
            for (int mf = 0; mf < MF; mf++)
                #pragma unroll
                for (int nf = 0; nf < NF; nf++)
                    acc[mf][nf] = __builtin_amdgcn_mfma_f32_16x16x32_bf16(
                        af[mf], bfr[nf], acc[mf][nf], 0, 0, 0);
        }
    }

    if (VSPLIT && col0 >= 2 * E_) {
        // V-projection tile -> write vT [bh][64][T] transposed.
        #pragma unroll
        for (int nf = 0; nf < NF; nf++) {
            const int cv = col0 + nc0 + nf * 16 + l16 - 2 * E_;
            const int hh = cv >> 6, dd = cv & 63;
            #pragma unroll
            for (int mf = 0; mf < MF; mf++) {
                const int row = row0 + mr0 + mf * 16 + quad * 4;
                const int bb = row >> 11, tt = row & (T_ - 1);
                ushort4 u;
                u.x = f2bs(acc[mf][nf][0]);
                u.y = f2bs(acc[mf][nf][1]);
                u.z = f2bs(acc[mf][nf][2]);
                u.w = f2bs(acc[mf][nf][3]);
                *(ushort4*)(vTout + ((size_t)(bb * H_ + hh) * 64 + dd) * T_ + tt) = u;
            }
        }
    } else {
        #pragma unroll
        for (int nf = 0; nf < NF; nf++) {
            const int col = col0 + nc0 + nf * 16 + l16;
            const float bv = BIAS ? bias[col] : 0.f;
            #pragma unroll
            for (int mf = 0; mf < MF; mf++) {
                #pragma unroll
                for (int r = 0; r < 4; r++) {
                    const int row = row0 + mr0 + mf * 16 + quad * 4 + r;
                    float v = acc[mf][nf][r] + bv;
                    if (ACC) v += ld1(&C[(size_t)row * N + col]);
                    if (RELU) v = fmaxf(v, 0.f);
                    st1(&C[(size_t)row * N + col], v);
                }
            }
        }
    }
}

// ---------------------------------------------------------------------------
// Flash attention (58 us base) + T13 defer-max: skip the O/o4 rescale pass
// when the wave's per-stage row-max growth <= RESCALE_THR (log2 units).
// Keeping the old running max bounds P by 2^THR (bf16-safe); the ones-column
// denominator o4 stays consistently scaled, so the final 1/o4 normalization
// is exact. First stage always rescales (mrow = -1e30).
// ---------------------------------------------------------------------------
__global__ __launch_bounds__(256) void attn_mfma(const bf16* __restrict__ qkv,
                                                 const bf16* __restrict__ vT,
                                                 bf16* __restrict__ outp)
{
    __shared__ short Klds[128][72];
    __shared__ short Vlds[64][136];
    __shared__ short Plds[4][16][136];

    const int tid  = threadIdx.x;
    const int w    = tid >> 6, lane = tid & 63;
    const int quad = lane >> 4, l16 = lane & 15;

    const int p    = blockIdx.y * 32 + blockIdx.x;   // 1024 blocks
    const int bh   = (p & 7) * 4 + ((p >> 3) & 3);   // XCD-pinned by p%8
    const int tile = 31 - (p >> 5);                  // heavy-first
    const int b    = bh >> 4, h = bh & 15;
    const size_t rowb = (size_t)b * T_ * 3 * E_;
    const int t0    = tile * 64;
    const int qbase = t0 + w * 16;

    // K staging map: key = tid>>1 (0..127), d-half = (tid&1)*32
    const int kkey = tid >> 1, kdh = (tid & 1) * 32;
    const bf16* Kg = qkv + rowb + E_ + h * HS_ + kdh;
    // V staging map: d = tid>>2 (0..63), key-seg = (tid&3)*32
    const int vd = tid >> 2, vseg = (tid & 3) * 32;
    const bf16* Vg = vT + ((size_t)bh * 64 + vd) * T_ + vseg;

    short8 vone;
    #pragma unroll
    for (int j = 0; j < 8; j++) vone[j] = (short)0x3F80;   // bf16 1.0

    const bf16* Qp = qkv + rowb + (size_t)(qbase + l16) * (3 * E_) + h * HS_;
    const short8 aq0 = *(const short8*)(Qp + quad * 8);
    const short8 aq1 = *(const short8*)(Qp + 32 + quad * 8);

    f32x4 o[4], o4;
    #pragma unroll
    for (int f = 0; f < 4; f++) o[f] = (f32x4){0.f, 0.f, 0.f, 0.f};
    o4 = (f32x4){0.f, 0.f, 0.f, 0.f};
    float mrow = NEG_BIG;

    for (int kt0 = 0; kt0 <= t0; kt0 += 128) {
        __syncthreads();   // all reads of prev K/Vlds done
        {
            // DIRECT load->LDS staging: transient regs only,
            // no named arrays living across a barrier.
            const int kr = (kt0 + kkey < T_) ? kt0 + kkey : T_ - 1;
            const bf16* kp = Kg + (size_t)kr * (3 * E_);
            *(uint4*)&Klds[kkey][kdh]      = ((const uint4*)kp)[0];
            *(uint4*)&Klds[kkey][kdh + 8]  = ((const uint4*)kp)[1];
            *(uint4*)&Klds[kkey][kdh + 16] = ((const uint4*)kp)[2];
            *(uint4*)&Klds[kkey][kdh + 24] = ((const uint4*)kp)[3];
            const bf16* vp = Vg + kt0;
            *(uint4*)&Vlds[vd][vseg]       = ((const uint4*)vp)[0];
            *(uint4*)&Vlds[vd][vseg + 8]   = ((const uint4*)vp)[1];
            *(uint4*)&Vlds[vd][vseg + 16]  = ((const uint4*)vp)[2];
            *(uint4*)&Vlds[vd][vseg + 24]  = ((const uint4*)vp)[3];
        }
        __syncthreads();   // staging visible

        const bool active = (kt0 <= qbase + 15);       // wave-uniform
        const int nv0 = ((qbase + 15 - kt0) >> 4) + 1; // valid chunks
        const int nvalid = active ? (nv0 < 8 ? nv0 : 8) : 0;

        // swapped QK^T: ps[c][r] = S[qrow=qbase+l16][key=kt0+c*16+quad*4+r]
        float ps[8][4];
        #pragma unroll
        for (int c = 0; c < 8; c++) {
            if (c < nvalid) {
                const int kc = kt0 + c * 16;
                const int krow = c * 16 + l16;
                short8 bk0 = *(const short8*)&Klds[krow][quad * 8];
                short8 bk1 = *(const short8*)&Klds[krow][32 + quad * 8];
                f32x4 s = (f32x4){0.f, 0.f, 0.f, 0.f};
                s = __builtin_amdgcn_mfma_f32_16x16x32_bf16(bk0, aq0, s, 0, 0, 0);
                s = __builtin_amdgcn_mfma_f32_16x16x32_bf16(bk1, aq1, s, 0, 0, 0);
                const bool needmask = (kc + 15 > qbase);   // wave-uniform
                #pragma unroll
                for (int r = 0; r < 4; r++) {
                    float sv = s[r] * SCL2E;
                    if (needmask && (kc + quad * 4 + r > qbase + l16)) sv = NEG_BIG;
                    ps[c][r] = sv;
                }
            }
        }
        if (active) {
            // lane-local max (lane's own keys) + cross-quad combine:
            // after 2 shfl, every lane holds the full max of q-row l16.
            float mx = ps[0][0];
            #pragma unroll
            for (int r = 1; r < 4; r++) mx = fmaxf(mx, ps[0][r]);
            #pragma unroll
            for (int c = 1; c < 8; c++)
                if (c < nvalid)
                    #pragma unroll
                    for (int r = 0; r < 4; r++) mx = fmaxf(mx, ps[c][r]);
            mx = fmaxf(mx, __shfl_xor(mx, 16));
            mx = fmaxf(mx, __shfl_xor(mx, 32));

            // T13 defer-max: rescale only if some row's max grew > THR.
            if (!__all(mx <= mrow + RESCALE_THR)) {
                const float mnew = fmaxf(mrow, mx);
                const float al = fexp2(mrow - mnew);
                mrow = mnew;
                // alpha: QK layout (row=l16) -> PV layout (row=quad*4+r)
                float alo[4];
                #pragma unroll
                for (int r = 0; r < 4; r++) alo[r] = __shfl(al, quad * 4 + r);
                #pragma unroll
                for (int f = 0; f < 4; f++)
                    #pragma unroll
                    for (int r = 0; r < 4; r++) o[f][r] *= alo[r];
                #pragma unroll
                for (int r = 0; r < 4; r++) o4[r] *= alo[r];
            }

            // P = exp2(s - mrow); 4 consecutive keys -> one b64 LDS write
            #pragma unroll
            for (int c = 0; c < 8; c++) {
                uint2 pk; pk.x = 0u; pk.y = 0u;
                if (c < nvalid) {
                    const float e0 = fexp2(ps[c][0] - mrow);
                    const float e1 = fexp2(ps[c][1] - mrow);
                    const float e2 = fexp2(ps[c][2] - mrow);
                    const float e3 = fexp2(ps[c][3] - mrow);
                    pk.x = (uint)f2bs(e0) | ((uint)f2bs(e1) << 16);
                    pk.y = (uint)f2bs(e2) | ((uint)f2bs(e3) << 16);
                }
                *(uint2*)&Plds[w][l16][c * 16 + quad * 4] = pk;
            }

            // PV (+ ones-column row-sum into o4). Same-wave P RAW ordered
            // by compiler lgkmcnt (wave-private Plds slice).
            #pragma unroll
            for (int kg = 0; kg < 4; kg++) {
                short8 pa = *(const short8*)&Plds[w][l16][kg * 32 + quad * 8];
                #pragma unroll
                for (int f = 0; f < 4; f++) {
                    short8 vb = *(const short8*)&Vlds[f * 16 + l16][kg * 32 + quad * 8];
                    o[f] = __builtin_amdgcn_mfma_f32_16x16x32_bf16(pa, vb, o[f], 0, 0, 0);
                }
                o4 = __builtin_amdgcn_mfma_f32_16x16x32_bf16(pa, vone, o4, 0, 0, 0);
            }
        }
    }

    #pragma unroll
    for (int r = 0; r < 4; r++) {
        const float linv = 1.f / o4[r];
        bf16* op = outp + (size_t)(b * T_ + qbase + quad * 4 + r) * E_ + h * HS_;
        #pragma unroll
        for (int f = 0; f < 4; f++)
            op[f * 16 + l16] = f2b(o[f][r] * linv);
    }
}

// ---------------------------------------------------------------------------
// LayerNorm(a + r)*g + be. One row (E=1024) per block.
// G13: each thread owns 4 CONSECUTIVE elements -> ushort4/float4 vector
// loads and stores.
// ---------------------------------------------------------------------------
template <typename TA, typename TR, typename TO>
__global__ __launch_bounds__(256) void ln_kernel(const TA* a,
                                                 const TR* r,
                                                 const float* g,
                                                 const float* be,
                                                 TO* out)
{
    const int row = blockIdx.x;
    const int c0  = (int)threadIdx.x * 4;
    const TA* pa = a + (size_t)row * E_ + c0;
    const TR* pr = r + (size_t)row * E_ + c0;
    TO* po = out + (size_t)row * E_ + c0;

    float va[4], vr[4], v[4];
    ld4(pa, va);
    ld4(pr, vr);
    float sum = 0.f, sq = 0.f;
    #pragma unroll
    for (int j = 0; j < 4; j++) {
        v[j] = va[j] + vr[j];
        sum += v[j];
        sq  += v[j] * v[j];
    }
    #pragma unroll
    for (int o = 32; o >= 1; o >>= 1) {
        sum += __shfl_xor(sum, o);
        sq  += __shfl_xor(sq, o);
    }
    __shared__ float red[8];
    const int wave = threadIdx.x >> 6, lane = threadIdx.x & 63;
    if (lane == 0) { red[wave] = sum; red[4 + wave] = sq; }
    __syncthreads();
    sum = red[0] + red[1] + red[2] + red[3];
    sq  = red[4] + red[5] + red[6] + red[7];

    const float mu  = sum * (1.f / E_);
    const float var = fmaxf(sq * (1.f / E_) - mu * mu, 0.f);
    const float rs  = rsqrtf(var + EPS_);

    const float4 gv = *(const float4*)(g + c0);
    const float4 bv = *(const float4*)(be + c0);
    float ov[4];
    ov[0] = (v[0] - mu) * rs * gv.x + bv.x;
    ov[1] = (v[1] - mu) * rs * gv.y + bv.y;
    ov[2] = (v[2] - mu) * rs * gv.z + bv.z;
    ov[3] = (v[3] - mu) * rs * gv.w + bv.w;
    st4(po, ov);
}

// ---------------------------------------------------------------------------
// ws plan (peak 32 MiB). d_out (16 MB fp32) is scratch until the end:
//   prepA:  xb @ d_out[0..8M); WqkvT ws[0..6M); WoT ws[30..32M)
//   qkv GEMM (VSPLIT): qkv Q/K -> ws[6..30M); V -> vT @ d_out[8..16M)
//   attn:   reads qkv + vT, writes attnout @ d_out[0..8M)  (xb dead)
//   prep2:  W1T ws[0..8M); W2T ws[8..16M)   (WqkvT dead after qkv;
//           qkv dead after attn)
//   proj    ws[16..24M); y ws[24..32M) (WoT dead after Wo-GEMM)
//   FFN (column-split): per half c0 in {0, 2048}:
//     h_half = relu(y @ W1T[c0:c0+2048]) [4096,2048] bf16 -> d_out[0..16M)
//       (attnout dead after proj, vT dead after attn)
//     ff (+)= h_half @ W2[c0:c0+2048,:]  [4096,1024] bf16 -> ws[16..24M)
//   LN2: reads y + ff from ws, writes fp32 to d_out. No aliasing.
// ---------------------------------------------------------------------------
extern "C" void kernel_launch(void* const* d_in, const int* in_sizes, int n_in,
                              void* d_out, int out_size, void* d_ws, size_t ws_size,
                              hipStream_t stream)
{
    (void)in_sizes; (void)n_in; (void)out_size; (void)ws_size;
    const float* x   = (const float*)d_in[0];
    const float* Wq  = (const float*)d_in[1];
    const float* Wk  = (const float*)d_in[2];
    const float* Wv  = (const float*)d_in[3];
    const float* Wo  = (const float*)d_in[4];
    const float* bo  = (const float*)d_in[5];
    const float* W1  = (const float*)d_in[6];
    const float* b1  = (const float*)d_in[7];
    const float* W2  = (const float*)d_in[8];
    const float* b2  = (const float*)d_in[9];
    const float* g1  = (const float*)d_in[10];
    const float* be1 = (const float*)d_in[11];
    const float* g2  = (const float*)d_in[12];
    const float* be2 = (const float*)d_in[13];

    const int M = B_ * T_;   // 4096
    char* ws = (char*)d_ws;
    bf16* WqkvT = (bf16*)(ws);                      // 0..6M
    bf16* qkv   = (bf16*)(ws + (size_t)6291456);    // 6..30M
    bf16* WoT   = (bf16*)(ws + (size_t)31457280);   // 30..32M
    bf16* W1T   = (bf16*)(ws);                      // 0..8M   (post-attn)
    bf16* W2T   = (bf16*)(ws + (size_t)8388608);    // 8..16M  (post-attn)
    bf16* proj  = (bf16*)(ws + (size_t)16777216);   // 16..24M
    bf16* y     = (bf16*)(ws + (size_t)25165824);   // 24..32M
    bf16* ff    = (bf16*)(ws + (size_t)16777216);   // 16..24M (proj dead)

    bf16*  xb      = (bf16*)d_out;                            // 0..8M of d_out
    bf16*  vT      = (bf16*)((char*)d_out + (size_t)8388608); // 8..16M of d_out
    bf16*  attnout = (bf16*)d_out;                            // 0..8M (xb dead)
    bf16*  hbuf    = (bf16*)d_out;                            // 0..16M (FFN)
    float* outf    = (float*)d_out;

    // 1) merged prep A: x->bf16, Wqkv^T, Wo^T
    prep_kernel<<<3072, 256, 0, stream>>>(x, (ushort*)xb, Wq, Wk, Wv, WqkvT, Wo, WoT);

    // 2) qkv = xb @ WqkvT^T  [4096,3072], K=1024  (768 blocks, 128x128, BK=64)
    //    VSPLIT: V-projection tiles write vT directly (vt_transpose fused).
    gemm_bt<2, 2, 4, 4, 2, false, false, false, true, bf16><<<dim3(24, 32), 256, 0, stream>>>(
        xb, WqkvT, nullptr, qkv, vT, M, 3 * E_, E_, E_);

    // 3) flash attention -> attnout (1024 blocks, XCD-pinned, heavy-first)
    attn_mfma<<<dim3(32, 32), 256, 0, stream>>>(qkv, vT, attnout);

    // 4) merged prep B: W1^T, W2^T (qkv dead)
    prep2_kernel<<<2048, 256, 0, stream>>>(W1, W1T, W2, W2T);

    // 5) proj = attnout @ WoT^T + bo  (128x64 tiles, BK=128 -> 8 stages)
    gemm_bt<2, 2, 4, 2, 4, true, false, false, false, bf16><<<dim3(16, 32), 256, 0, stream>>>(
        attnout, WoT, bo, proj, nullptr, M, E_, E_, E_);

    // 6) y = LN1(x + proj) -> ws[24..32M)
    ln_kernel<float, bf16, bf16><<<M, 256, 0, stream>>>(x, proj, g1, be1, y);

    // 7) FFN column-split: full-M GEMMs, ff accumulated across column halves.
    for (int half = 0; half < 2; half++) {
        const size_t c0 = (size_t)half * 2048;   // h-column block
        // h_half = relu(y @ W1T[c0:c0+2048]^T + b1[c0:]) : [4096,2048]
        // 128x128 tiles, BK=128 -> 8 stages (LDS 64KB caps 2/CU = grid's 2/CU)
        gemm_bt<2, 2, 4, 4, 4, true, true, false, false, bf16><<<dim3(16, 32), 256, 0, stream>>>(
            y, W1T + c0 * E_, b1 + c0, hbuf, nullptr, M, 2048, E_, E_);
        // ff (+)= h_half @ W2[c0:c0+2048,:] : [4096,1024], K=2048
        // 128x64 tiles, BK=128 -> 16 stages (LDS 48KB, cap 3 >= grid's 2/CU)
        if (half == 0)
            gemm_bt<2, 2, 4, 2, 4, true, false, false, false, bf16><<<dim3(16, 32), 256, 0, stream>>>(
                hbuf, W2T + c0, b2, ff, nullptr, M, E_, 2048, 4 * E_);
        else
            gemm_bt<2, 2, 4, 2, 4, false, false, true, false, bf16><<<dim3(16, 32), 256, 0, stream>>>(
                hbuf, W2T + c0, nullptr, ff, nullptr, M, E_, 2048, 4 * E_);
    }

    // 8) out = LN2(y + ff) -> d_out fp32 (sources in ws, no aliasing)
    ln_kernel<bf16, bf16, float><<<M, 256, 0, stream>>>(y, ff, g2, be2, outf);
}

// Round 15
// 357.431 us; speedup vs baseline: 1.0608x; 1.0126x over previous
//
#include <hip/hip_runtime.h>
#include <hip/hip_bf16.h>
#include <cstdint>
#include <cstddef>

typedef __hip_bfloat16 bf16;
typedef __attribute__((ext_vector_type(8))) short short8;
typedef __attribute__((ext_vector_type(4))) float f32x4;

#define B_  2
#define T_  2048
#define E_  1024
#define H_  16
#define HS_ 64
#define EPS_ 1e-5f
#define NEG_BIG -1.0e30f
// 0.125 (1/sqrt(64)) * log2(e): scores in exp2 domain
#define SCL2E 0.18033688011112042f

__device__ __forceinline__ float b2f(bf16 v) { return __bfloat162float(v); }
__device__ __forceinline__ bf16  f2b(float v) { return __float2bfloat16(v); }
__device__ __forceinline__ ushort f2bs(float v) { bf16 b = __float2bfloat16(v); return *(ushort*)&b; }
__device__ __forceinline__ float ld1(const bf16* p) { return b2f(*p); }
__device__ __forceinline__ float ld1(const float* p) { return *p; }
__device__ __forceinline__ void st1(bf16* p, float v) { *p = f2b(v); }
__device__ __forceinline__ void st1(float* p, float v) { *p = v; }

// vectorized 4-elem load/store helpers (G13: no scalar bf16 loads)
__device__ __forceinline__ void ld4(const bf16* p, float v[4]) {
    ushort4 u = *(const ushort4*)p;
    v[0] = b2f(*(const bf16*)&u.x);
    v[1] = b2f(*(const bf16*)&u.y);
    v[2] = b2f(*(const bf16*)&u.z);
    v[3] = b2f(*(const bf16*)&u.w);
}
__device__ __forceinline__ void ld4(const float* p, float v[4]) {
    float4 f = *(const float4*)p;
    v[0] = f.x; v[1] = f.y; v[2] = f.z; v[3] = f.w;
}
__device__ __forceinline__ void st4(bf16* p, const float v[4]) {
    ushort4 u;
    u.x = f2bs(v[0]); u.y = f2bs(v[1]); u.z = f2bs(v[2]); u.w = f2bs(v[3]);
    *(ushort4*)p = u;
}
__device__ __forceinline__ void st4(float* p, const float v[4]) {
    float4 f; f.x = v[0]; f.y = v[1]; f.z = v[2]; f.w = v[3];
    *(float4*)p = f;
}

__device__ __forceinline__ float fexp2(float x) {
#if __has_builtin(__builtin_amdgcn_exp2f)
    return __builtin_amdgcn_exp2f(x);
#else
    return exp2f(x);
#endif
}

// async global->LDS, 16B per lane; lds dest = wave-uniform base + lane*16
__device__ __forceinline__ void gload16(const void* g, const void* l) {
    __builtin_amdgcn_global_load_lds(
        (const __attribute__((address_space(1))) unsigned int*)(size_t)g,
        (__attribute__((address_space(3))) unsigned int*)(unsigned int)(size_t)l,
        16, 0, 0);
}

// ---------------------------------------------------------------------------
// 64x64 fp32->bf16 transpose tile (shared buffer passed in)
// ---------------------------------------------------------------------------
__device__ __forceinline__ void transpose_tile_s(short t[64][72],
                                                 const float* in, size_t ldin,
                                                 bf16* out, size_t ldout,
                                                 int r0, int c0)
{
    const int tid = threadIdx.x;
    const int tr = tid >> 2, tc4 = (tid & 3) * 16;

    const float* p = in + (size_t)(r0 + tr) * ldin + c0 + tc4;
    float4 v0 = ((const float4*)p)[0], v1 = ((const float4*)p)[1];
    float4 v2 = ((const float4*)p)[2], v3 = ((const float4*)p)[3];
    union { ushort u[16]; uint4 q[2]; } pk;
    pk.u[0] = f2bs(v0.x); pk.u[1] = f2bs(v0.y); pk.u[2]  = f2bs(v0.z); pk.u[3]  = f2bs(v0.w);
    pk.u[4] = f2bs(v1.x); pk.u[5] = f2bs(v1.y); pk.u[6]  = f2bs(v1.z); pk.u[7]  = f2bs(v1.w);
    pk.u[8] = f2bs(v2.x); pk.u[9] = f2bs(v2.y); pk.u[10] = f2bs(v2.z); pk.u[11] = f2bs(v2.w);
    pk.u[12] = f2bs(v3.x); pk.u[13] = f2bs(v3.y); pk.u[14] = f2bs(v3.z); pk.u[15] = f2bs(v3.w);
    *(uint4*)&t[tr][tc4]     = pk.q[0];
    *(uint4*)&t[tr][tc4 + 8] = pk.q[1];
    __syncthreads();

    const int tcI = tid >> 2, rj = (tid & 3) * 16;
    union { ushort u[16]; uint4 q[2]; } po;
    #pragma unroll
    for (int j = 0; j < 16; j++) po.u[j] = (ushort)t[rj + j][tcI];
    bf16* op = out + (size_t)(c0 + tcI) * ldout + r0 + rj;
    ((uint4*)op)[0] = po.q[0];
    ((uint4*)op)[1] = po.q[1];
}

// ---------------------------------------------------------------------------
// Merged prep A: x->bf16 (2048 blocks) + Wqkv^T (768) + Wo^T (256)
// ---------------------------------------------------------------------------
__global__ __launch_bounds__(256) void prep_kernel(const float* __restrict__ x,
                                                   ushort* __restrict__ xb,
                                                   const float* __restrict__ Wq,
                                                   const float* __restrict__ Wk,
                                                   const float* __restrict__ Wv,
                                                   bf16* __restrict__ WqkvT,
                                                   const float* __restrict__ Wo,
                                                   bf16* __restrict__ WoT)
{
    __shared__ short t[64][72];
    const int bid = blockIdx.x;
    if (bid < 2048) {
        int i = (bid * 256 + (int)threadIdx.x) * 8;
        float4 a = ((const float4*)(x + i))[0];
        float4 b = ((const float4*)(x + i))[1];
        union { ushort u[8]; uint4 v; } p;
        p.u[0] = f2bs(a.x); p.u[1] = f2bs(a.y); p.u[2] = f2bs(a.z); p.u[3] = f2bs(a.w);
        p.u[4] = f2bs(b.x); p.u[5] = f2bs(b.y); p.u[6] = f2bs(b.z); p.u[7] = f2bs(b.w);
        *(uint4*)(xb + i) = p.v;
    } else if (bid < 2048 + 768) {
        const int i = bid - 2048;            // (s 0..47) x (xt 0..15)
        const int s = i >> 4, xt = i & 15;
        const int proj = s >> 4, h = s & 15;
        const float* W = (proj == 0) ? Wq : ((proj == 1) ? Wk : Wv);
        transpose_tile_s(t, W + (size_t)h * E_ * HS_, HS_,
                         WqkvT + ((size_t)proj * E_ + h * 64) * E_, E_,
                         xt * 64, 0);
    } else {
        const int i = bid - 2816;            // 256 tiles of Wo [1024][1024]
        transpose_tile_s(t, Wo, E_, WoT, E_, (i >> 4) * 64, (i & 15) * 64);
    }
}

// ---------------------------------------------------------------------------
// Merged prep B: W1^T (1024 blocks) + W2^T (1024 blocks)
// ---------------------------------------------------------------------------
__global__ __launch_bounds__(256) void prep2_kernel(const float* __restrict__ W1,
                                                    bf16* __restrict__ W1T,
                                                    const float* __restrict__ W2,
                                                    bf16* __restrict__ W2T)
{
    __shared__ short t[64][72];
    const int bid = blockIdx.x;
    if (bid < 1024) {   // W1 [1024][4096] -> W1T [4096][1024]
        transpose_tile_s(t, W1, 4 * E_, W1T, E_,
                         (bid & 15) * 64, (bid >> 4) * 64);
    } else {            // W2 [4096][1024] -> W2T [1024][4096]
        const int i = bid - 1024;
        transpose_tile_s(t, W2, E_, W2T, 4 * E_,
                         (i >> 4) * 64, (i & 15) * 64);
    }
}

// ---------------------------------------------------------------------------
// MFMA GEMM: C[M,N] = A[M,K] @ BT[N,K]^T (+bias fp32)(+relu)(+C-accumulate),
// bf16 in, TO out. BT row stride = ldb. XCD-pinned bijective grid remap
// (requires gridDim.x % 8 == 0).
// DBUF (catalog T3 minimum-2-phase): double-buffered LDS, ONE barrier per
// K-step: barrier -> stage(next tile -> buf^1) -> compute(buf). The next
// tile's global_load_lds flight hides under the current tile's MFMA run;
// the compiler-emitted vmcnt(0)+lgkmcnt(0) at each __syncthreads separates
// every write/read pair on both buffers. 2-step manual unroll keeps LDS
// buffer indices compile-time. Requires K/(32*KS) even (16/16/32 here).
// DBUF call sites use KS=2 (BK=64): W1 128^2 dbuf = 64KB -> 2/CU (= grid);
// proj/W2 128x64 dbuf = 48KB -> cap 3 >= 2. qkv stays single-buffer
// (dbuf 64KB would cut its 3/CU grid to 2 — the m132 trap).
// VSPLIT (qkv call only): blocks with col0 >= 2048 hold the V-projection;
// they write vT [bh][64][T] directly (transposed) instead of C.
// ---------------------------------------------------------------------------
template <int WROWS, int WCOLS, int MF, int NF, int KS, bool DBUF, bool BIAS,
          bool RELU, bool ACC, bool VSPLIT, typename TO>
__global__ __launch_bounds__(256) void gemm_bt(const bf16* __restrict__ A,
                                               const bf16* __restrict__ BT,
                                               const float* __restrict__ bias,
                                               TO* __restrict__ C,
                                               bf16* __restrict__ vTout,
                                               int M, int N, int K, int ldb)
{
    constexpr int BM = WROWS * MF * 16;
    constexpr int BN = WCOLS * NF * 16;
    constexpr int NB = DBUF ? 2 : 1;
    __shared__ short Asm[NB][KS][BM][32];
    __shared__ short Bsm[NB][KS][BN][32];

    const int tid  = threadIdx.x;
    const int wv   = tid >> 6, lane = tid & 63;
    const int quad = lane >> 4, l16 = lane & 15;

    // XCD-pinned bijective remap (gx % 8 == 0 at every call site)
    const int gx = gridDim.x;
    const int p  = blockIdx.y * gx + blockIdx.x;
    const int spx = gx >> 3;                 // column strips per XCD
    const int xcd = p & 7, j = p >> 3;
    const int bx = xcd * spx + (j % spx);
    const int by = j / spx;

    const int row0 = by * BM, col0 = bx * BN;
    const int mr0  = (wv / WCOLS) * MF * 16;
    const int nc0  = (wv % WCOLS) * NF * 16;

    const int sr = tid >> 2, sc = tid & 3;
    const bf16* Ag = A  + (size_t)(row0 + sr) * K + sc * 8;
    const bf16* Bg = BT + (size_t)(col0 + (sr % BN)) * ldb + sc * 8;

    f32x4 acc[MF][NF];
    #pragma unroll
    for (int i = 0; i < MF; i++)
        #pragma unroll
        for (int j2 = 0; j2 < NF; j2++) acc[i][j2] = (f32x4){0.f, 0.f, 0.f, 0.f};

    auto stage = [&](int nb) {
        #pragma unroll
        for (int g = 0; g < KS; g++) {
            #pragma unroll
            for (int l = 0; l < BM / 64; l++)
                gload16(Ag + g * 32 + (size_t)l * 64 * K, &Asm[nb][g][l * 64 + wv * 16][0]);
            #pragma unroll
            for (int l = 0; l < BN / 64; l++)
                gload16(Bg + g * 32 + (size_t)l * 64 * ldb, &Bsm[nb][g][l * 64 + wv * 16][0]);
        }
        Ag += 32 * KS; Bg += 32 * KS;
    };
    auto compute = [&](int nb) {
        #pragma unroll
        for (int g = 0; g < KS; g++) {
            short8 af[MF], bfr[NF];
            #pragma unroll
            for (int mf = 0; mf < MF; mf++)
                af[mf] = *(const short8*)&Asm[nb][g][mr0 + mf * 16 + l16][quad * 8];
            #pragma unroll
            for (int nf = 0; nf < NF; nf++)
                bfr[nf] = *(const short8*)&Bsm[nb][g][nc0 + nf * 16 + l16][quad * 8];
            #pragma unroll
            for (int mf = 0; mf < MF; mf++)
                #pragma unroll
                for (int nf = 0; nf < NF; nf++)
                    acc[mf][nf] = __builtin_amdgcn_mfma_f32_16x16x32_bf16(
                        af[mf], bfr[nf], acc[mf][nf], 0, 0, 0);
        }
    };

    if (DBUF) {
        const int nt = K / (32 * KS);        // even at all DBUF call sites
        stage(0);                            // prologue: tile 0 -> buf0
        for (int t = 0; t < nt; t += 2) {
            __syncthreads();                 // buf0 landed; buf1 readers done
            if (t + 1 < nt) stage(1);        // tile t+1 -> buf1 (overlaps)
            compute(0);                      // tile t
            __syncthreads();                 // buf1 landed; buf0 readers done
            if (t + 2 < nt) stage(0);        // tile t+2 -> buf0 (overlaps)
            compute(1);                      // tile t+1
        }
    } else {
        for (int kt = 0; kt < K; kt += 32 * KS) {
            __syncthreads();
            stage(0);
            __syncthreads();
            compute(0);
        }
    }

    if (VSPLIT && col0 >= 2 * E_) {
        // V-projection tile -> write vT [bh][64][T] transposed.
        #pragma unroll
        for (int nf = 0; nf < NF; nf++) {
            const int cv = col0 + nc0 + nf * 16 + l16 - 2 * E_;
            const int hh = cv >> 6, dd = cv & 63;
            #pragma unroll
            for (int mf = 0; mf < MF; mf++) {
                const int row = row0 + mr0 + mf * 16 + quad * 4;
                const int bb = row >> 11, tt = row & (T_ - 1);
                ushort4 u;
                u.x = f2bs(acc[mf][nf][0]);
                u.y = f2bs(acc[mf][nf][1]);
                u.z = f2bs(acc[mf][nf][2]);
                u.w = f2bs(acc[mf][nf][3]);
                *(ushort4*)(vTout + ((size_t)(bb * H_ + hh) * 64 + dd) * T_ + tt) = u;
            }
        }
    } else {
        #pragma unroll
        for (int nf = 0; nf < NF; nf++) {
            const int col = col0 + nc0 + nf * 16 + l16;
            const float bv = BIAS ? bias[col] : 0.f;
            #pragma unroll
            for (int mf = 0; mf < MF; mf++) {
                #pragma unroll
                for (int r = 0; r < 4; r++) {
                    const int row = row0 + mr0 + mf * 16 + quad * 4 + r;
                    float v = acc[mf][nf][r] + bv;
                    if (ACC) v += ld1(&C[(size_t)row * N + col]);
                    if (RELU) v = fmaxf(v, 0.f);
                    st1(&C[(size_t)row * N + col], v);
                }
            }
        }
    }
}

// ---------------------------------------------------------------------------
// Flash attention (converged config, 58.4 us; T13 defer-max REVERTED — r14
// measured +1 us): 128-key stages, no setprio, unpaired 1024-block grid,
// XCD-pinned (bh by p%8), heavy-first tiles, direct global->LDS staging
// (no reg arrays across barriers), swapped-QK lane-local softmax,
// ones-column denominator, exp2 domain.
// ---------------------------------------------------------------------------
__global__ __launch_bounds__(256) void attn_mfma(const bf16* __restrict__ qkv,
                                                 const bf16* __restrict__ vT,
                                                 bf16* __restrict__ outp)
{
    __shared__ short Klds[128][72];
    __shared__ short Vlds[64][136];
    __shared__ short Plds[4][16][136];

    const int tid  = threadIdx.x;
    const int w    = tid >> 6, lane = tid & 63;
    const int quad = lane >> 4, l16 = lane & 15;

    const int p    = blockIdx.y * 32 + blockIdx.x;   // 1024 blocks
    const int bh   = (p & 7) * 4 + ((p >> 3) & 3);   // XCD-pinned by p%8
    const int tile = 31 - (p >> 5);                  // heavy-first
    const int b    = bh >> 4, h = bh & 15;
    const size_t rowb = (size_t)b * T_ * 3 * E_;
    const int t0    = tile * 64;
    const int qbase = t0 + w * 16;

    // K staging map: key = tid>>1 (0..127), d-half = (tid&1)*32
    const int kkey = tid >> 1, kdh = (tid & 1) * 32;
    const bf16* Kg = qkv + rowb + E_ + h * HS_ + kdh;
    // V staging map: d = tid>>2 (0..63), key-seg = (tid&3)*32
    const int vd = tid >> 2, vseg = (tid & 3) * 32;
    const bf16* Vg = vT + ((size_t)bh * 64 + vd) * T_ + vseg;

    short8 vone;
    #pragma unroll
    for (int j = 0; j < 8; j++) vone[j] = (short)0x3F80;   // bf16 1.0

    const bf16* Qp = qkv + rowb + (size_t)(qbase + l16) * (3 * E_) + h * HS_;
    const short8 aq0 = *(const short8*)(Qp + quad * 8);
    const short8 aq1 = *(const short8*)(Qp + 32 + quad * 8);

    f32x4 o[4], o4;
    #pragma unroll
    for (int f = 0; f < 4; f++) o[f] = (f32x4){0.f, 0.f, 0.f, 0.f};
    o4 = (f32x4){0.f, 0.f, 0.f, 0.f};
    float mrow = NEG_BIG;

    for (int kt0 = 0; kt0 <= t0; kt0 += 128) {
        __syncthreads();   // all reads of prev K/Vlds done
        {
            // DIRECT load->LDS staging: transient regs only,
            // no named arrays living across a barrier.
            const int kr = (kt0 + kkey < T_) ? kt0 + kkey : T_ - 1;
            const bf16* kp = Kg + (size_t)kr * (3 * E_);
            *(uint4*)&Klds[kkey][kdh]      = ((const uint4*)kp)[0];
            *(uint4*)&Klds[kkey][kdh + 8]  = ((const uint4*)kp)[1];
            *(uint4*)&Klds[kkey][kdh + 16] = ((const uint4*)kp)[2];
            *(uint4*)&Klds[kkey][kdh + 24] = ((const uint4*)kp)[3];
            const bf16* vp = Vg + kt0;
            *(uint4*)&Vlds[vd][vseg]       = ((const uint4*)vp)[0];
            *(uint4*)&Vlds[vd][vseg + 8]   = ((const uint4*)vp)[1];
            *(uint4*)&Vlds[vd][vseg + 16]  = ((const uint4*)vp)[2];
            *(uint4*)&Vlds[vd][vseg + 24]  = ((const uint4*)vp)[3];
        }
        __syncthreads();   // staging visible

        const bool active = (kt0 <= qbase + 15);       // wave-uniform
        const int nv0 = ((qbase + 15 - kt0) >> 4) + 1; // valid chunks
        const int nvalid = active ? (nv0 < 8 ? nv0 : 8) : 0;

        // swapped QK^T: ps[c][r] = S[qrow=qbase+l16][key=kt0+c*16+quad*4+r]
        float ps[8][4];
        #pragma unroll
        for (int c = 0; c < 8; c++) {
            if (c < nvalid) {
                const int kc = kt0 + c * 16;
                const int krow = c * 16 + l16;
                short8 bk0 = *(const short8*)&Klds[krow][quad * 8];
                short8 bk1 = *(const short8*)&Klds[krow][32 + quad * 8];
                f32x4 s = (f32x4){0.f, 0.f, 0.f, 0.f};
                s = __builtin_amdgcn_mfma_f32_16x16x32_bf16(bk0, aq0, s, 0, 0, 0);
                s = __builtin_amdgcn_mfma_f32_16x16x32_bf16(bk1, aq1, s, 0, 0, 0);
                const bool needmask = (kc + 15 > qbase);   // wave-uniform
                #pragma unroll
                for (int r = 0; r < 4; r++) {
                    float sv = s[r] * SCL2E;
                    if (needmask && (kc + quad * 4 + r > qbase + l16)) sv = NEG_BIG;
                    ps[c][r] = sv;
                }
            }
        }
        if (active) {
            // lane-local max (lane's own keys) + cross-quad combine:
            // after 2 shfl, every lane holds the full max of q-row l16.
            float mx = ps[0][0];
            #pragma unroll
            for (int r = 1; r < 4; r++) mx = fmaxf(mx, ps[0][r]);
            #pragma unroll
            for (int c = 1; c < 8; c++)
                if (c < nvalid)
                    #pragma unroll
                    for (int r = 0; r < 4; r++) mx = fmaxf(mx, ps[c][r]);
            mx = fmaxf(mx, __shfl_xor(mx, 16));
            mx = fmaxf(mx, __shfl_xor(mx, 32));
            const float mnew = fmaxf(mrow, mx);
            const float al = fexp2(mrow - mnew);
            mrow = mnew;

            // P = exp2(s - m); 4 consecutive keys -> one b64 LDS write
            #pragma unroll
            for (int c = 0; c < 8; c++) {
                uint2 pk; pk.x = 0u; pk.y = 0u;
                if (c < nvalid) {
                    const float e0 = fexp2(ps[c][0] - mnew);
                    const float e1 = fexp2(ps[c][1] - mnew);
                    const float e2 = fexp2(ps[c][2] - mnew);
                    const float e3 = fexp2(ps[c][3] - mnew);
                    pk.x = (uint)f2bs(e0) | ((uint)f2bs(e1) << 16);
                    pk.y = (uint)f2bs(e2) | ((uint)f2bs(e3) << 16);
                }
                *(uint2*)&Plds[w][l16][c * 16 + quad * 4] = pk;
            }

            // alpha: QK layout (row=l16, lanes 0..15) -> PV layout
            // (row=quad*4+r)
            float alo[4];
            #pragma unroll
            for (int r = 0; r < 4; r++) alo[r] = __shfl(al, quad * 4 + r);
            #pragma unroll
            for (int f = 0; f < 4; f++)
                #pragma unroll
                for (int r = 0; r < 4; r++) o[f][r] *= alo[r];
            #pragma unroll
            for (int r = 0; r < 4; r++) o4[r] *= alo[r];

            // PV (+ ones-column row-sum into o4). Same-wave P RAW ordered
            // by compiler lgkmcnt (wave-private Plds slice).
            #pragma unroll
            for (int kg = 0; kg < 4; kg++) {
                short8 pa = *(const short8*)&Plds[w][l16][kg * 32 + quad * 8];
                #pragma unroll
                for (int f = 0; f < 4; f++) {
                    short8 vb = *(const short8*)&Vlds[f * 16 + l16][kg * 32 + quad * 8];
                    o[f] = __builtin_amdgcn_mfma_f32_16x16x32_bf16(pa, vb, o[f], 0, 0, 0);
                }
                o4 = __builtin_amdgcn_mfma_f32_16x16x32_bf16(pa, vone, o4, 0, 0, 0);
            }
        }
    }

    #pragma unroll
    for (int r = 0; r < 4; r++) {
        const float linv = 1.f / o4[r];
        bf16* op = outp + (size_t)(b * T_ + qbase + quad * 4 + r) * E_ + h * HS_;
        #pragma unroll
        for (int f = 0; f < 4; f++)
            op[f * 16 + l16] = f2b(o[f][r] * linv);
    }
}

// ---------------------------------------------------------------------------
// LayerNorm(a + r)*g + be. One row (E=1024) per block.
// G13: each thread owns 4 CONSECUTIVE elements -> ushort4/float4 vector
// loads and stores.
// ---------------------------------------------------------------------------
template <typename TA, typename TR, typename TO>
__global__ __launch_bounds__(256) void ln_kernel(const TA* a,
                                                 const TR* r,
                                                 const float* g,
                                                 const float* be,
                                                 TO* out)
{
    const int row = blockIdx.x;
    const int c0  = (int)threadIdx.x * 4;
    const TA* pa = a + (size_t)row * E_ + c0;
    const TR* pr = r + (size_t)row * E_ + c0;
    TO* po = out + (size_t)row * E_ + c0;

    float va[4], vr[4], v[4];
    ld4(pa, va);
    ld4(pr, vr);
    float sum = 0.f, sq = 0.f;
    #pragma unroll
    for (int j = 0; j < 4; j++) {
        v[j] = va[j] + vr[j];
        sum += v[j];
        sq  += v[j] * v[j];
    }
    #pragma unroll
    for (int o = 32; o >= 1; o >>= 1) {
        sum += __shfl_xor(sum, o);
        sq  += __shfl_xor(sq, o);
    }
    __shared__ float red[8];
    const int wave = threadIdx.x >> 6, lane = threadIdx.x & 63;
    if (lane == 0) { red[wave] = sum; red[4 + wave] = sq; }
    __syncthreads();
    sum = red[0] + red[1] + red[2] + red[3];
    sq  = red[4] + red[5] + red[6] + red[7];

    const float mu  = sum * (1.f / E_);
    const float var = fmaxf(sq * (1.f / E_) - mu * mu, 0.f);
    const float rs  = rsqrtf(var + EPS_);

    const float4 gv = *(const float4*)(g + c0);
    const float4 bv = *(const float4*)(be + c0);
    float ov[4];
    ov[0] = (v[0] - mu) * rs * gv.x + bv.x;
    ov[1] = (v[1] - mu) * rs * gv.y + bv.y;
    ov[2] = (v[2] - mu) * rs * gv.z + bv.z;
    ov[3] = (v[3] - mu) * rs * gv.w + bv.w;
    st4(po, ov);
}

// ---------------------------------------------------------------------------
// ws plan (peak 32 MiB). d_out (16 MB fp32) is scratch until the end:
//   prepA:  xb @ d_out[0..8M); WqkvT ws[0..6M); WoT ws[30..32M)
//   qkv GEMM (VSPLIT): qkv Q/K -> ws[6..30M); V -> vT @ d_out[8..16M)
//   attn:   reads qkv + vT, writes attnout @ d_out[0..8M)  (xb dead)
//   prep2:  W1T ws[0..8M); W2T ws[8..16M)   (WqkvT dead after qkv;
//           qkv dead after attn)
//   proj    ws[16..24M); y ws[24..32M) (WoT dead after Wo-GEMM)
//   FFN (column-split): per half c0 in {0, 2048}:
//     h_half = relu(y @ W1T[c0:c0+2048]) [4096,2048] bf16 -> d_out[0..16M)
//       (attnout dead after proj, vT dead after attn)
//     ff (+)= h_half @ W2[c0:c0+2048,:]  [4096,1024] bf16 -> ws[16..24M)
//   LN2: reads y + ff from ws, writes fp32 to d_out. No aliasing.
// ---------------------------------------------------------------------------
extern "C" void kernel_launch(void* const* d_in, const int* in_sizes, int n_in,
                              void* d_out, int out_size, void* d_ws, size_t ws_size,
                              hipStream_t stream)
{
    (void)in_sizes; (void)n_in; (void)out_size; (void)ws_size;
    const float* x   = (const float*)d_in[0];
    const float* Wq  = (const float*)d_in[1];
    const float* Wk  = (const float*)d_in[2];
    const float* Wv  = (const float*)d_in[3];
    const float* Wo  = (const float*)d_in[4];
    const float* bo  = (const float*)d_in[5];
    const float* W1  = (const float*)d_in[6];
    const float* b1  = (const float*)d_in[7];
    const float* W2  = (const float*)d_in[8];
    const float* b2  = (const float*)d_in[9];
    const float* g1  = (const float*)d_in[10];
    const float* be1 = (const float*)d_in[11];
    const float* g2  = (const float*)d_in[12];
    const float* be2 = (const float*)d_in[13];

    const int M = B_ * T_;   // 4096
    char* ws = (char*)d_ws;
    bf16* WqkvT = (bf16*)(ws);                      // 0..6M
    bf16* qkv   = (bf16*)(ws + (size_t)6291456);    // 6..30M
    bf16* WoT   = (bf16*)(ws + (size_t)31457280);   // 30..32M
    bf16* W1T   = (bf16*)(ws);                      // 0..8M   (post-attn)
    bf16* W2T   = (bf16*)(ws + (size_t)8388608);    // 8..16M  (post-attn)
    bf16* proj  = (bf16*)(ws + (size_t)16777216);   // 16..24M
    bf16* y     = (bf16*)(ws + (size_t)25165824);   // 24..32M
    bf16* ff    = (bf16*)(ws + (size_t)16777216);   // 16..24M (proj dead)

    bf16*  xb      = (bf16*)d_out;                            // 0..8M of d_out
    bf16*  vT      = (bf16*)((char*)d_out + (size_t)8388608); // 8..16M of d_out
    bf16*  attnout = (bf16*)d_out;                            // 0..8M (xb dead)
    bf16*  hbuf    = (bf16*)d_out;                            // 0..16M (FFN)
    float* outf    = (float*)d_out;

    // 1) merged prep A: x->bf16, Wqkv^T, Wo^T
    prep_kernel<<<3072, 256, 0, stream>>>(x, (ushort*)xb, Wq, Wk, Wv, WqkvT, Wo, WoT);

    // 2) qkv = xb @ WqkvT^T  [4096,3072], K=1024  (768 blocks, 128x128, BK=64)
    //    VSPLIT: V-projection tiles write vT directly (vt_transpose fused).
    gemm_bt<2, 2, 4, 4, 2, false, false, false, false, true, bf16><<<dim3(24, 32), 256, 0, stream>>>(
        xb, WqkvT, nullptr, qkv, vT, M, 3 * E_, E_, E_);

    // 3) flash attention -> attnout (1024 blocks, XCD-pinned, heavy-first)
    attn_mfma<<<dim3(32, 32), 256, 0, stream>>>(qkv, vT, attnout);

    // 4) merged prep B: W1^T, W2^T (qkv dead)
    prep2_kernel<<<2048, 256, 0, stream>>>(W1, W1T, W2, W2T);

    // 5) proj = attnout @ WoT^T + bo  (128x64 tiles, BK=64 DBUF, 16 stages)
    gemm_bt<2, 2, 4, 2, 2, true, true, false, false, false, bf16><<<dim3(16, 32), 256, 0, stream>>>(
        attnout, WoT, bo, proj, nullptr, M, E_, E_, E_);

    // 6) y = LN1(x + proj) -> ws[24..32M)
    ln_kernel<float, bf16, bf16><<<M, 256, 0, stream>>>(x, proj, g1, be1, y);

    // 7) FFN column-split: full-M GEMMs, ff accumulated across column halves.
    for (int half = 0; half < 2; half++) {
        const size_t c0 = (size_t)half * 2048;   // h-column block
        // h_half = relu(y @ W1T[c0:c0+2048]^T + b1[c0:]) : [4096,2048]
        // 128x128 tiles, BK=64 DBUF (LDS 64KB -> 2/CU = grid's 2/CU)
        gemm_bt<2, 2, 4, 4, 2, true, true, true, false, false, bf16><<<dim3(16, 32), 256, 0, stream>>>(
            y, W1T + c0 * E_, b1 + c0, hbuf, nullptr, M, 2048, E_, E_);
        // ff (+)= h_half @ W2[c0:c0+2048,:] : [4096,1024], K=2048
        // 128x64 tiles, BK=64 DBUF (LDS 48KB -> cap 3 >= grid's 2/CU)
        if (half == 0)
            gemm_bt<2, 2, 4, 2, 2, true, true, false, false, false, bf16><<<dim3(16, 32), 256, 0, stream>>>(
                hbuf, W2T + c0, b2, ff, nullptr, M, E_, 2048, 4 * E_);
        else
            gemm_bt<2, 2, 4, 2, 2, true, false, false, true, false, bf16><<<dim3(16, 32), 256, 0, stream>>>(
                hbuf, W2T + c0, nullptr, ff, nullptr, M, E_, 2048, 4 * E_);
    }

    // 8) out = LN2(y + ff) -> d_out fp32 (sources in ws, no aliasing)
    ln_kernel<bf16, bf16, float><<<M, 256, 0, stream>>>(y, ff, g2, be2, outf);
}